// Round 3
// baseline (2698.388 us; speedup 1.0000x reference)
//
#include <hip/hip_runtime.h>

typedef unsigned int u32;
typedef unsigned short u16;

#define NPTS 65536
#define DMODEL 256
#define NHEAD 8
#define DHEAD 32
#define NLAYER 4
#define FFDIM 2048
#define WSIZE 128
#define LNEPS 1e-5f
#define RG 256  // radix sort blocks (chunk = 256 elements each)

// LDS strides (bf16 elems) chosen to avoid systematic bank conflicts
#define KSTR 36
#define VSTR 132
#define PSTR 132

typedef __attribute__((ext_vector_type(8))) short short8;
typedef __attribute__((ext_vector_type(4))) float floatx4;

__device__ __forceinline__ float bf2f(u16 v) {
    u32 u = ((u32)v) << 16;
    float f;
    __builtin_memcpy(&f, &u, 4);
    return f;
}
__device__ __forceinline__ u16 f2bf(float f) {
    u32 u;
    __builtin_memcpy(&u, &f, 4);
    u32 r = (u + 0x7fffu + ((u >> 16) & 1u)) >> 16;
    return (u16)r;
}

__device__ __forceinline__ void gl_lds16(const void* g, void* l) {
    __builtin_amdgcn_global_load_lds((const __attribute__((address_space(1))) u32*)g,
                                     (__attribute__((address_space(3))) u32*)l, 16, 0, 0);
}

// ---------------- Morton keys ----------------
__global__ __launch_bounds__(256) void morton_kernel(const int* __restrict__ coords,
                                                     u32* __restrict__ key, u32* __restrict__ val) {
    int i = blockIdx.x * 256 + threadIdx.x;
    int b = coords[4 * i + 0];
    int x = coords[4 * i + 1];
    int y = coords[4 * i + 2];
    int z = coords[4 * i + 3];
    u32 m = 0;
#pragma unroll
    for (int t = 0; t < 7; ++t) {
        m |= ((u32)((x >> t) & 1) << (3 * t + 2)) | ((u32)((y >> t) & 1) << (3 * t + 1)) |
             ((u32)((z >> t) & 1) << (3 * t));
    }
    key[i] = ((u32)b << 21) | m;
    val[i] = (u32)i;
}

// ---------------- radix sort (stable LSD, 3 x 8-bit) ----------------
__global__ __launch_bounds__(256) void hist_kernel(const u32* __restrict__ key, u32* __restrict__ ghist,
                                                   int shift) {
    __shared__ u32 h[256];
    int tid = threadIdx.x;
    h[tid] = 0;
    __syncthreads();
    u32 k = key[blockIdx.x * 256 + tid];
    atomicAdd(&h[(k >> shift) & 255u], 1u);
    __syncthreads();
    ghist[(size_t)tid * RG + blockIdx.x] = h[tid];  // bucket-major
}

// parallel exclusive scan over 256*RG = 65536 entries:
// scan_up: 64 blocks x 1024 entries (256 thr x uint4) -> in-place block-local
//          exclusive scan + block total to aux[64]
// (aux prefix is folded into scatter_kernel; no scan_down pass)
__global__ __launch_bounds__(256) void scan_up(u32* __restrict__ g, u32* __restrict__ aux) {
    __shared__ u32 wsum[4];
    int tid = threadIdx.x;
    int lane = tid & 63;
    int wave = tid >> 6;
    size_t base = (size_t)blockIdx.x * 1024 + (size_t)tid * 4;
    uint4 v = *(const uint4*)(g + base);
    u32 s = v.x + v.y + v.z + v.w;
    u32 inc = s;
#pragma unroll
    for (int off = 1; off < 64; off <<= 1) {
        u32 u = __shfl_up(inc, off, 64);
        if (lane >= off) inc += u;
    }
    if (lane == 63) wsum[wave] = inc;
    __syncthreads();
    u32 woff = 0;
    for (int w = 0; w < wave; ++w) woff += wsum[w];
    u32 excl = woff + inc - s;
    uint4 o;
    o.x = excl;
    o.y = excl + v.x;
    o.z = excl + v.x + v.y;
    o.w = excl + v.x + v.y + v.z;
    *(uint4*)(g + base) = o;
    if (tid == 255) aux[blockIdx.x] = woff + inc;  // block total
}

// scatter: stable rank via wave ballot multi-split (8 ballots) + per-wave LDS histogram.
// Global bucket offset = block-local scanned ghist + wave-scanned aux prefix (fused scan_down).
__global__ __launch_bounds__(256) void scatter_kernel(const u32* __restrict__ keyin, const u32* __restrict__ valin,
                                                      u32* __restrict__ keyout, u32* __restrict__ valout,
                                                      const u32* __restrict__ ghist, const u32* __restrict__ aux,
                                                      int shift) {
    __shared__ u32 whist[4][256];
    __shared__ u32 apre[64];
    int tid = threadIdx.x;
    int lane = tid & 63;
    int wave = tid >> 6;
    // clear per-wave histograms (1024 u32, 4 per thread)
    uint4 z = {0u, 0u, 0u, 0u};
    ((uint4*)&whist[0][0])[tid] = z;
    if (tid < 64) {  // wave 0: exclusive scan of aux[64] into LDS
        u32 a = aux[tid];
        u32 inc = a;
#pragma unroll
        for (int off = 1; off < 64; off <<= 1) {
            u32 u = __shfl_up(inc, off, 64);
            if (lane >= off) inc += u;
        }
        apre[tid] = inc - a;
    }
    int gi = blockIdx.x * 256 + tid;
    u32 k = keyin[gi];
    u32 v = valin[gi];
    u32 b = (k >> shift) & 255u;
    __syncthreads();
    unsigned long long m = ~0ull;
#pragma unroll
    for (int bit = 0; bit < 8; ++bit) {
        unsigned long long bb = __ballot((int)((b >> bit) & 1u));
        m &= ((b >> bit) & 1u) ? bb : ~bb;
    }
    unsigned long long below = (lane == 0) ? 0ull : (m & ((1ull << lane) - 1ull));
    int rlane = __popcll(below);
    int cnt = __popcll(m);
    if (rlane == 0) whist[wave][b] = (u32)cnt;  // leader lane of each bucket group
    __syncthreads();
    u32 rank = (u32)rlane;
    for (int w = 0; w < wave; ++w) rank += whist[w][b];
    u32 e = b * (u32)RG + blockIdx.x;
    u32 dst = ghist[e] + apre[e >> 10] + rank;
    keyout[dst] = k;
    valout[dst] = v;
}

// ---------------- weight fp32 -> bf16 ----------------
__global__ __launch_bounds__(256) void cvt_bf16_kernel(const float* __restrict__ in, u16* __restrict__ out, int n) {
    int i = blockIdx.x * 256 + threadIdx.x;
    if (i < n) out[i] = f2bf(in[i]);
}

// ---------------- gather + positional encodings ----------------
template <bool HF32>
__global__ __launch_bounds__(256) void gather_pe_kernel(const u32* __restrict__ idx, const int* __restrict__ coords,
                                                        const float* __restrict__ feat,
                                                        const float* __restrict__ pex, const float* __restrict__ pey,
                                                        const float* __restrict__ pez, const float* __restrict__ pes,
                                                        float* __restrict__ h, u16* __restrict__ xb) {
    int row = blockIdx.x * 4 + (threadIdx.x >> 6);
    int lane = threadIdx.x & 63;
    int src = (int)idx[row];
    int cx = coords[4 * src + 1];
    int cy = coords[4 * src + 2];
    int cz = coords[4 * src + 3];
    int c = lane * 4;
    float4 f = *(const float4*)(feat + (size_t)src * DMODEL + c);
    float4 px = *(const float4*)(pex + (size_t)cx * DMODEL + c);
    float4 py = *(const float4*)(pey + (size_t)cy * DMODEL + c);
    float4 pz = *(const float4*)(pez + (size_t)cz * DMODEL + c);
    float4 ps = *(const float4*)(pes + (size_t)1 * DMODEL + c);  // pe_s[1]
    float4 r;
    r.x = f.x + px.x + py.x + pz.x + ps.x;
    r.y = f.y + px.y + py.y + pz.y + ps.y;
    r.z = f.z + px.z + py.z + pz.z + ps.z;
    r.w = f.w + px.w + py.w + pz.w + ps.w;
    if (HF32) *(float4*)(h + (size_t)row * DMODEL + c) = r;
    ushort4 o;
    o.x = f2bf(r.x);
    o.y = f2bf(r.y);
    o.z = f2bf(r.z);
    o.w = f2bf(r.w);
    *(ushort4*)(xb + (size_t)row * DMODEL + c) = o;
}

// ---------------- GEMM: C = A @ W^T + bias  (A: MxK bf16, W: OxK bf16) ----------------
// 128x128 tile, BK=64, 4 waves each computing 64x64 via 4x4 of 16x16x32 MFMA.
// Double-buffered LDS: stage(t+1) issued before compute(t); counted s_waitcnt vmcnt(8).
// Split-K via gridDim.z: slice kz computes K/KZ columns, fp32 partials to slice kz of Cout;
// bias added in slice 0 only (RELU requires gridDim.z==1).
// bx is XCD-chunk-swizzled (bijective when gridDim.x % 8 == 0) so each XCD owns a
// contiguous M-tile range -> A panel + weights L2-resident per XCD.
__device__ __forceinline__ void stage_tiles(const u16* __restrict__ Abase, const u16* __restrict__ Wbase,
                                            int K, int k0, u16* la, u16* lb, int tid) {
#pragma unroll
    for (int it = 0; it < 4; ++it) {
        int cidx = tid + it * 256;   // chunk 0..1023; each chunk = 8 bf16 = 16B
        int r = cidx >> 3;           // row 0..127
        int cc = (cidx & 7) << 3;    // col 0..56 step 8
        gl_lds16(Abase + (size_t)r * K + k0 + cc, la + cidx * 8);
        gl_lds16(Wbase + (size_t)r * K + k0 + cc, lb + cidx * 8);
    }
}

template <bool RELU, bool BF16OUT>
__global__ __launch_bounds__(256) void gemm_bt(const u16* __restrict__ A, const u16* __restrict__ W,
                                               const float* __restrict__ bias, void* __restrict__ Cout,
                                               int M, int O, int K) {
    __shared__ __align__(16) u16 lA[2][128 * 64];
    __shared__ __align__(16) u16 lB[2][128 * 64];
    const int tid = threadIdx.x;
    const int lane = tid & 63;
    const int wave = tid >> 6;
    const int wr = wave >> 1;
    const int wc = wave & 1;
    const int quad = lane >> 4;
    const int l16 = lane & 15;
    u32 gx = gridDim.x;
    u32 bx = blockIdx.x;
    if ((gx & 7u) == 0u) bx = (bx & 7u) * (gx >> 3) + (bx >> 3);  // XCD-chunk swizzle
    const int kz = blockIdx.z;
    const int Kpart = K / (int)gridDim.z;
    const size_t row0 = (size_t)bx * 128;
    const size_t col0 = (size_t)blockIdx.y * 128;
    floatx4 acc[4][4] = {};
    const u16* Abase = A + row0 * (size_t)K + (size_t)kz * Kpart;
    const u16* Wbase = W + col0 * (size_t)K + (size_t)kz * Kpart;

    const int nt = Kpart >> 6;
    stage_tiles(Abase, Wbase, K, 0, &lA[0][0], &lB[0][0], tid);
    int buf = 0;
    for (int t = 0; t < nt; ++t) {
        if (t + 1 < nt) {
            stage_tiles(Abase, Wbase, K, (t + 1) << 6, &lA[buf ^ 1][0], &lB[buf ^ 1][0], tid);
            asm volatile("s_waitcnt vmcnt(8)" ::: "memory");  // wait current tile only
        } else {
            asm volatile("s_waitcnt vmcnt(0)" ::: "memory");
        }
        __builtin_amdgcn_s_barrier();  // all waves' stage(t) complete
        const u16* la = &lA[buf][0];
        const u16* lb = &lB[buf][0];
#pragma unroll
        for (int kk = 0; kk < 64; kk += 32) {
            short8 af[4], bf[4];
#pragma unroll
            for (int r = 0; r < 4; ++r)
                af[r] = *(const short8*)&la[(wr * 64 + r * 16 + l16) * 64 + kk + quad * 8];
#pragma unroll
            for (int c = 0; c < 4; ++c)
                bf[c] = *(const short8*)&lb[(wc * 64 + c * 16 + l16) * 64 + kk + quad * 8];
#pragma unroll
            for (int r = 0; r < 4; ++r)
#pragma unroll
                for (int c = 0; c < 4; ++c)
                    acc[r][c] = __builtin_amdgcn_mfma_f32_16x16x32_bf16(af[r], bf[c], acc[r][c], 0, 0, 0);
        }
        if (t + 1 < nt) __builtin_amdgcn_s_barrier();  // reads done -> buf may be overwritten
        buf ^= 1;
    }

    float* Cf = (float*)Cout + (size_t)kz * ((size_t)M * O);  // split-K slice (fp32 path)
#pragma unroll
    for (int r = 0; r < 4; ++r) {
#pragma unroll
        for (int c = 0; c < 4; ++c) {
            size_t col = col0 + wc * 64 + c * 16 + l16;
            float bv = (kz == 0) ? bias[col] : 0.f;
#pragma unroll
            for (int reg = 0; reg < 4; ++reg) {
                size_t row = row0 + wr * 64 + r * 16 + quad * 4 + reg;
                float v = acc[r][c][reg] + bv;
                if (RELU) v = fmaxf(v, 0.f);
                if (BF16OUT)
                    ((u16*)Cout)[row * O + col] = f2bf(v);
                else
                    Cf[row * O + col] = v;
            }
        }
    }
}

// ---------------- window attention, MFMA (one block = one (window, head)) ----------------
__global__ __launch_bounds__(128) void attn_kernel(const u16* __restrict__ qkv, u16* __restrict__ outb) {
    const int wh = blockIdx.x;
    const int w = wh >> 3;   // window index within chunk
    const int h = wh & 7;
    const int tid = threadIdx.x;
    const int wave = tid >> 6;
    const int lane = tid & 63;
    const int quad = lane >> 4;
    const int l16 = lane & 15;
    __shared__ __align__(16) u16 lK[128 * KSTR];
    __shared__ __align__(16) u16 lVt[32 * VSTR];
    __shared__ __align__(16) u16 lP[128 * PSTR];
    const u16* base = qkv + (size_t)w * WSIZE * (3 * DMODEL);

    // cooperative staging: thread t handles token t
    {
        const u16* krow = base + (size_t)tid * (3 * DMODEL) + DMODEL + h * DHEAD;
        const u16* vrow = base + (size_t)tid * (3 * DMODEL) + 2 * DMODEL + h * DHEAD;
#pragma unroll
        for (int p = 0; p < 4; ++p)
            *(short8*)&lK[tid * KSTR + p * 8] = *(const short8*)(krow + p * 8);
        u16 varr[32];
#pragma unroll
        for (int p = 0; p < 4; ++p)
            *(short8*)&varr[p * 8] = *(const short8*)(vrow + p * 8);
#pragma unroll
        for (int d = 0; d < DHEAD; ++d) lVt[d * VSTR + tid] = varr[d];
    }
    // Q fragments direct from global (A-frag: row = l16 within m-tile, k = quad*8..+8)
    short8 af[4];
#pragma unroll
    for (int mi = 0; mi < 4; ++mi)
        af[mi] = *(const short8*)(base + (size_t)(wave * 64 + mi * 16 + l16) * (3 * DMODEL) + h * DHEAD + quad * 8);
    __syncthreads();

    // S = Q @ K^T : 4 m-tiles x 8 n-tiles, K-dim = 32 = one mfma step
    floatx4 acc[4][8] = {};
#pragma unroll
    for (int ni = 0; ni < 8; ++ni) {
        short8 bk = *(const short8*)&lK[(ni * 16 + l16) * KSTR + quad * 8];
#pragma unroll
        for (int mi = 0; mi < 4; ++mi)
            acc[mi][ni] = __builtin_amdgcn_mfma_f32_16x16x32_bf16(af[mi], bk, acc[mi][ni], 0, 0, 0);
    }

    // softmax over each row (row = wave*64 + mi*16 + quad*4 + reg; cols = ni*16 + l16)
    const float scale = 0.17677669529663687f;  // 1/sqrt(32)
    float inv[4][4];
#pragma unroll
    for (int mi = 0; mi < 4; ++mi) {
#pragma unroll
        for (int reg = 0; reg < 4; ++reg) {
            float m = acc[mi][0][reg];
#pragma unroll
            for (int ni = 1; ni < 8; ++ni) m = fmaxf(m, acc[mi][ni][reg]);
            m = fmaxf(m, __shfl_xor(m, 1, 64));
            m = fmaxf(m, __shfl_xor(m, 2, 64));
            m = fmaxf(m, __shfl_xor(m, 4, 64));
            m = fmaxf(m, __shfl_xor(m, 8, 64));
            float e[8];
            float sum = 0.f;
#pragma unroll
            for (int ni = 0; ni < 8; ++ni) {
                e[ni] = __expf((acc[mi][ni][reg] - m) * scale);
                sum += e[ni];
            }
            sum += __shfl_xor(sum, 1, 64);
            sum += __shfl_xor(sum, 2, 64);
            sum += __shfl_xor(sum, 4, 64);
            sum += __shfl_xor(sum, 8, 64);
            inv[mi][reg] = 1.f / sum;
            int row = wave * 64 + mi * 16 + quad * 4 + reg;
#pragma unroll
            for (int ni = 0; ni < 8; ++ni) lP[row * PSTR + ni * 16 + l16] = f2bf(e[ni]);
        }
    }
    // same-wave LDS write->read dependency (each wave reads only its own 64 rows of lP)

    // O = P @ V : 4 m-tiles x 2 n-tiles, K-dim = 128 (4 mfma steps)
    floatx4 acc2[4][2] = {};
#pragma unroll
    for (int kt = 0; kt < 4; ++kt) {
        short8 pa[4];
#pragma unroll
        for (int mi = 0; mi < 4; ++mi)
            pa[mi] = *(const short8*)&lP[(wave * 64 + mi * 16 + l16) * PSTR + kt * 32 + quad * 8];
#pragma unroll
        for (int c = 0; c < 2; ++c) {
            short8 bv = *(const short8*)&lVt[(c * 16 + l16) * VSTR + kt * 32 + quad * 8];
#pragma unroll
            for (int mi = 0; mi < 4; ++mi)
                acc2[mi][c] = __builtin_amdgcn_mfma_f32_16x16x32_bf16(pa[mi], bv, acc2[mi][c], 0, 0, 0);
        }
    }

    // epilogue: normalize and store bf16
#pragma unroll
    for (int mi = 0; mi < 4; ++mi) {
#pragma unroll
        for (int c = 0; c < 2; ++c) {
#pragma unroll
            for (int reg = 0; reg < 4; ++reg) {
                int row = wave * 64 + mi * 16 + quad * 4 + reg;
                outb[(size_t)(w * WSIZE + row) * DMODEL + h * DHEAD + c * 16 + l16] =
                    f2bf(acc2[mi][c][reg] * inv[mi][reg]);
            }
        }
    }
}

// ---------------- residual add + LayerNorm (chunk-local, pointers pre-offset) ----------------
// HF32: residual stream held in fp32 (hin/hout) vs bf16; OUTF32: fp32 output (final layer)
// NS: number of split-K delta slices to sum (slice stride dstride fp32 elems)
template <bool HF32, bool OUTF32, int NS>
__global__ __launch_bounds__(256) void resid_ln_kernel(const void* __restrict__ hin, const float* __restrict__ delta,
                                                       const float* __restrict__ g, const float* __restrict__ b,
                                                       float* __restrict__ hout, void* __restrict__ nout,
                                                       size_t dstride) {
    int row = blockIdx.x * 4 + (threadIdx.x >> 6);
    int lane = threadIdx.x & 63;
    int c = lane * 4;
    float4 x;
    if (HF32) {
        x = *(const float4*)((const float*)hin + (size_t)row * DMODEL + c);
    } else {
        ushort4 hv = *(const ushort4*)((const u16*)hin + (size_t)row * DMODEL + c);
        x.x = bf2f(hv.x);
        x.y = bf2f(hv.y);
        x.z = bf2f(hv.z);
        x.w = bf2f(hv.w);
    }
    float4 d = *(const float4*)(delta + (size_t)row * DMODEL + c);
    if (NS == 2) {
        float4 d2 = *(const float4*)(delta + dstride + (size_t)row * DMODEL + c);
        d.x += d2.x;
        d.y += d2.y;
        d.z += d2.z;
        d.w += d2.w;
    }
    x.x += d.x;
    x.y += d.y;
    x.z += d.z;
    x.w += d.w;
    float s = x.x + x.y + x.z + x.w;
#pragma unroll
    for (int off = 32; off > 0; off >>= 1) s += __shfl_xor(s, off, 64);
    float mu = s * (1.f / 256.f);
    float d0 = x.x - mu, d1 = x.y - mu, d2 = x.z - mu, d3 = x.w - mu;
    float vs = d0 * d0 + d1 * d1 + d2 * d2 + d3 * d3;
#pragma unroll
    for (int off = 32; off > 0; off >>= 1) vs += __shfl_xor(vs, off, 64);
    float rs = rsqrtf(vs * (1.f / 256.f) + LNEPS);
    float4 gg = *(const float4*)(g + c);
    float4 bb = *(const float4*)(b + c);
    float4 y;
    y.x = d0 * rs * gg.x + bb.x;
    y.y = d1 * rs * gg.y + bb.y;
    y.z = d2 * rs * gg.z + bb.z;
    y.w = d3 * rs * gg.w + bb.w;
    if (HF32) *(float4*)(hout + (size_t)row * DMODEL + c) = y;
    if (OUTF32) {
        *(float4*)((float*)nout + (size_t)row * DMODEL + c) = y;
    } else {
        ushort4 o;
        o.x = f2bf(y.x);
        o.y = f2bf(y.y);
        o.z = f2bf(y.z);
        o.w = f2bf(y.w);
        *(ushort4*)((u16*)nout + (size_t)row * DMODEL + c) = o;
    }
}

// ---------------- launch ----------------
extern "C" void kernel_launch(void* const* d_in, const int* in_sizes, int n_in,
                              void* d_out, int out_size, void* d_ws, size_t ws_size,
                              hipStream_t stream) {
    (void)in_sizes;
    (void)n_in;
    (void)out_size;
    const int* coords = (const int*)d_in[0];
    const float* feat = (const float*)d_in[1];
    const float* pex = (const float*)d_in[2];
    const float* pey = (const float*)d_in[3];
    const float* pez = (const float*)d_in[4];
    const float* pes = (const float*)d_in[5];
    const float* Wqkv = (const float*)d_in[6];
    const float* bqkv = (const float*)d_in[7];
    const float* Wo = (const float*)d_in[8];
    const float* bo = (const float*)d_in[9];
    const float* W1 = (const float*)d_in[10];
    const float* b1 = (const float*)d_in[11];
    const float* W2 = (const float*)d_in[12];
    const float* b2 = (const float*)d_in[13];
    const float* g1 = (const float*)d_in[14];
    const float* be1 = (const float*)d_in[15];
    const float* g2 = (const float*)d_in[16];
    const float* be2 = (const float*)d_in[17];

    auto al = [](size_t x) { return (x + 255) & ~(size_t)255; };
    // fixed allocations
    const size_t sortB = 4 * al((size_t)NPTS * 4) + al((size_t)256 * RG * 4) + 256;
    const size_t wqkvB = al((size_t)NLAYER * 3 * DMODEL * DMODEL * 2);
    const size_t woB = al((size_t)NLAYER * DMODEL * DMODEL * 2);
    const size_t w1B = al((size_t)NLAYER * FFDIM * DMODEL * 2);
    const size_t w2B = al((size_t)NLAYER * DMODEL * FFDIM * 2);
    const size_t wB = wqkvB + woB + w1B + w2B;
    const size_t xbB = al((size_t)NPTS * DMODEL * 2);
    const size_t hB = al((size_t)NPTS * DMODEL * 4);

    // choose mode + chunk size + split-K to fit ws_size.
    // Priority: larger CH (fewer dispatches) > split-K=2 for W2 (grid parallelism on K).
    int CH = 0, KSP = 1;
    bool modeA = true;
    for (int ch = 65536; ch >= 128 && !CH; ch >>= 1) {
        for (int ksp = 2; ksp >= 1; --ksp) {
            size_t need = sortB + wB + xbB + hB + al((size_t)ch * 4096) + al((size_t)ch * 1024 * ksp) + 65536;
            if (need <= ws_size) { CH = ch; KSP = ksp; modeA = true; break; }
        }
    }
    if (!CH) {
        for (int ch = 65536; ch >= 128 && !CH; ch >>= 1) {
            for (int ksp = 2; ksp >= 1; --ksp) {
                size_t need = sortB + wB + xbB + al((size_t)ch * 4096) + al((size_t)ch * 1024 * ksp) + 65536;
                if (need <= ws_size) { CH = ch; KSP = ksp; modeA = false; break; }
            }
        }
    }
    if (!CH) { CH = 128; KSP = 1; modeA = false; }  // nothing fits; best effort

    char* ws = (char*)d_ws;
    size_t off = 0;
    auto alloc = [&](size_t bytes) -> void* {
        void* p = ws + off;
        off += al(bytes);
        return p;
    };
    u32* key0 = (u32*)alloc(NPTS * 4);
    u32* val0 = (u32*)alloc(NPTS * 4);
    u32* key1 = (u32*)alloc(NPTS * 4);
    u32* val1 = (u32*)alloc(NPTS * 4);
    u32* ghist = (u32*)alloc(256 * RG * 4);
    u32* aux = (u32*)alloc(64 * 4);
    u16* wqkv_b = (u16*)alloc((size_t)NLAYER * 3 * DMODEL * DMODEL * 2);
    u16* wo_b = (u16*)alloc((size_t)NLAYER * DMODEL * DMODEL * 2);
    u16* w1_b = (u16*)alloc((size_t)NLAYER * FFDIM * DMODEL * 2);
    u16* w2_b = (u16*)alloc((size_t)NLAYER * DMODEL * FFDIM * 2);
    u16* xb = (u16*)alloc((size_t)NPTS * DMODEL * 2);
    float* h = modeA ? (float*)alloc((size_t)NPTS * DMODEL * 4) : nullptr;
    u16* scratch1 = (u16*)alloc((size_t)CH * 4096);  // qkv (CH*768) + attout (CH*256) | ffn-mid (CH*2048)
    float* tmpc = (float*)alloc((size_t)CH * 1024 * KSP);  // KSP x (CH x 256) fp32 delta slices
    const size_t dstride = (size_t)CH * DMODEL;  // fp32 elems per slice

    // 1. morton keys
    morton_kernel<<<NPTS / 256, 256, 0, stream>>>(coords, key0, val0);

    // 2. stable radix sort, 3 x 8-bit passes (24-bit keys)
    u32 *ki = key0, *vi = val0, *ko = key1, *vo = val1;
    for (int p = 0; p < 3; ++p) {
        hist_kernel<<<RG, 256, 0, stream>>>(ki, ghist, p * 8);
        scan_up<<<64, 256, 0, stream>>>(ghist, aux);
        scatter_kernel<<<RG, 256, 0, stream>>>(ki, vi, ko, vo, ghist, aux, p * 8);
        u32* t;
        t = ki; ki = ko; ko = t;
        t = vi; vi = vo; vo = t;
    }
    const u32* idx = vi;  // sorted original indices

    // 3. weights -> bf16
    cvt_bf16_kernel<<<(NLAYER * 3 * DMODEL * DMODEL) / 256, 256, 0, stream>>>(Wqkv, wqkv_b, NLAYER * 3 * DMODEL * DMODEL);
    cvt_bf16_kernel<<<(NLAYER * DMODEL * DMODEL) / 256, 256, 0, stream>>>(Wo, wo_b, NLAYER * DMODEL * DMODEL);
    cvt_bf16_kernel<<<(NLAYER * FFDIM * DMODEL) / 256, 256, 0, stream>>>(W1, w1_b, NLAYER * FFDIM * DMODEL);
    cvt_bf16_kernel<<<(NLAYER * DMODEL * FFDIM) / 256, 256, 0, stream>>>(W2, w2_b, NLAYER * DMODEL * FFDIM);

    // 4. gather + PE
    if (modeA)
        gather_pe_kernel<true><<<NPTS / 4, 256, 0, stream>>>(idx, coords, feat, pex, pey, pez, pes, h, xb);
    else
        gather_pe_kernel<false><<<NPTS / 4, 256, 0, stream>>>(idx, coords, feat, pex, pey, pez, pes, nullptr, xb);

    // 5. encoder layers, chunked over rows (CH rows = CH/128 windows per chunk)
    const int nch = NPTS / CH;
    u16* qkvc = scratch1;                     // CH x 768 bf16
    u16* attoutc = scratch1 + (size_t)CH * 768;  // CH x 256 bf16
    u16* midc = scratch1;                     // CH x 2048 bf16 (reuses qkv region)
    for (int l = 0; l < NLAYER; ++l) {
        for (int c = 0; c < nch; ++c) {
            u16* xc = xb + (size_t)c * CH * DMODEL;
            float* hc = modeA ? h + (size_t)c * CH * DMODEL : nullptr;
            // qkv = x @ Wqkv^T + bqkv  -> bf16
            gemm_bt<false, true><<<dim3(CH / 128, (3 * DMODEL) / 128), 256, 0, stream>>>(
                xc, wqkv_b + (size_t)l * 3 * DMODEL * DMODEL, bqkv + (size_t)l * 3 * DMODEL, qkvc,
                CH, 3 * DMODEL, DMODEL);
            // window attention (MFMA) -> attout bf16
            attn_kernel<<<(CH / WSIZE) * NHEAD, 128, 0, stream>>>(qkvc, attoutc);
            // o = attout @ Wo^T + bo -> fp32
            gemm_bt<false, false><<<dim3(CH / 128, DMODEL / 128), 256, 0, stream>>>(
                attoutc, wo_b + (size_t)l * DMODEL * DMODEL, bo + (size_t)l * DMODEL, tmpc,
                CH, DMODEL, DMODEL);
            // h = LN(h + o)
            if (modeA)
                resid_ln_kernel<true, false, 1><<<CH / 4, 256, 0, stream>>>(hc, tmpc, g1 + (size_t)l * DMODEL,
                                                                            be1 + (size_t)l * DMODEL, hc, xc, dstride);
            else
                resid_ln_kernel<false, false, 1><<<CH / 4, 256, 0, stream>>>(xc, tmpc, g1 + (size_t)l * DMODEL,
                                                                             be1 + (size_t)l * DMODEL, nullptr, xc, dstride);
            // FFN
            gemm_bt<true, true><<<dim3(CH / 128, FFDIM / 128), 256, 0, stream>>>(
                xc, w1_b + (size_t)l * FFDIM * DMODEL, b1 + (size_t)l * FFDIM, midc,
                CH, FFDIM, DMODEL);
            gemm_bt<false, false><<<dim3(CH / 128, DMODEL / 128, KSP), 256, 0, stream>>>(
                midc, w2_b + (size_t)l * DMODEL * FFDIM, b2 + (size_t)l * DMODEL, tmpc,
                CH, DMODEL, FFDIM);
            // h = LN(h + ff)
            bool last = (l == NLAYER - 1);
            void* outc = last ? (void*)((float*)d_out + (size_t)c * CH * DMODEL) : (void*)xc;
            if (modeA) {
                if (last) {
                    if (KSP == 2)
                        resid_ln_kernel<true, true, 2><<<CH / 4, 256, 0, stream>>>(hc, tmpc, g2 + (size_t)l * DMODEL,
                                                                                   be2 + (size_t)l * DMODEL, hc, outc, dstride);
                    else
                        resid_ln_kernel<true, true, 1><<<CH / 4, 256, 0, stream>>>(hc, tmpc, g2 + (size_t)l * DMODEL,
                                                                                   be2 + (size_t)l * DMODEL, hc, outc, dstride);
                } else {
                    if (KSP == 2)
                        resid_ln_kernel<true, false, 2><<<CH / 4, 256, 0, stream>>>(hc, tmpc, g2 + (size_t)l * DMODEL,
                                                                                    be2 + (size_t)l * DMODEL, hc, outc, dstride);
                    else
                        resid_ln_kernel<true, false, 1><<<CH / 4, 256, 0, stream>>>(hc, tmpc, g2 + (size_t)l * DMODEL,
                                                                                    be2 + (size_t)l * DMODEL, hc, outc, dstride);
                }
            } else {
                if (last) {
                    if (KSP == 2)
                        resid_ln_kernel<false, true, 2><<<CH / 4, 256, 0, stream>>>(xc, tmpc, g2 + (size_t)l * DMODEL,
                                                                                    be2 + (size_t)l * DMODEL, nullptr, outc, dstride);
                    else
                        resid_ln_kernel<false, true, 1><<<CH / 4, 256, 0, stream>>>(xc, tmpc, g2 + (size_t)l * DMODEL,
                                                                                    be2 + (size_t)l * DMODEL, nullptr, outc, dstride);
                } else {
                    if (KSP == 2)
                        resid_ln_kernel<false, false, 2><<<CH / 4, 256, 0, stream>>>(xc, tmpc, g2 + (size_t)l * DMODEL,
                                                                                     be2 + (size_t)l * DMODEL, nullptr, outc, dstride);
                    else
                        resid_ln_kernel<false, false, 1><<<CH / 4, 256, 0, stream>>>(xc, tmpc, g2 + (size_t)l * DMODEL,
                                                                                     be2 + (size_t)l * DMODEL, nullptr, outc, dstride);
                }
            }
        }
    }
}

// Round 4
// 2515.879 us; speedup vs baseline: 1.0725x; 1.0725x over previous
//
#include <hip/hip_runtime.h>

typedef unsigned int u32;
typedef unsigned short u16;

#define NPTS 65536
#define DMODEL 256
#define NHEAD 8
#define DHEAD 32
#define NLAYER 4
#define FFDIM 2048
#define WSIZE 128
#define LNEPS 1e-5f
#define RG 256  // radix sort blocks (chunk = 256 elements each)

// LDS strides (bf16 elems) chosen to avoid systematic bank conflicts
#define KSTR 36
#define VSTR 132
#define PSTR 132

typedef __attribute__((ext_vector_type(8))) short short8;
typedef __attribute__((ext_vector_type(4))) float floatx4;

__device__ __forceinline__ float bf2f(u16 v) {
    u32 u = ((u32)v) << 16;
    float f;
    __builtin_memcpy(&f, &u, 4);
    return f;
}
__device__ __forceinline__ u16 f2bf(float f) {
    u32 u;
    __builtin_memcpy(&u, &f, 4);
    u32 r = (u + 0x7fffu + ((u >> 16) & 1u)) >> 16;
    return (u16)r;
}

__device__ __forceinline__ void gl_lds16(const void* g, void* l) {
    __builtin_amdgcn_global_load_lds((const __attribute__((address_space(1))) u32*)g,
                                     (__attribute__((address_space(3))) u32*)l, 16, 0, 0);
}

// ---------------- Morton keys ----------------
__global__ __launch_bounds__(256) void morton_kernel(const int* __restrict__ coords,
                                                     u32* __restrict__ key, u32* __restrict__ val) {
    int i = blockIdx.x * 256 + threadIdx.x;
    int b = coords[4 * i + 0];
    int x = coords[4 * i + 1];
    int y = coords[4 * i + 2];
    int z = coords[4 * i + 3];
    u32 m = 0;
#pragma unroll
    for (int t = 0; t < 7; ++t) {
        m |= ((u32)((x >> t) & 1) << (3 * t + 2)) | ((u32)((y >> t) & 1) << (3 * t + 1)) |
             ((u32)((z >> t) & 1) << (3 * t));
    }
    key[i] = ((u32)b << 21) | m;
    val[i] = (u32)i;
}

// ---------------- radix sort (stable LSD, 3 x 8-bit) ----------------
__global__ __launch_bounds__(256) void hist_kernel(const u32* __restrict__ key, u32* __restrict__ ghist,
                                                   int shift) {
    __shared__ u32 h[256];
    int tid = threadIdx.x;
    h[tid] = 0;
    __syncthreads();
    u32 k = key[blockIdx.x * 256 + tid];
    atomicAdd(&h[(k >> shift) & 255u], 1u);
    __syncthreads();
    ghist[(size_t)tid * RG + blockIdx.x] = h[tid];  // bucket-major
}

// parallel exclusive scan over 256*RG = 65536 entries:
// scan_up: 64 blocks x 1024 entries (256 thr x uint4) -> in-place block-local
//          exclusive scan + block total to aux[64]
// (aux prefix is folded into scatter_kernel; no scan_down pass)
__global__ __launch_bounds__(256) void scan_up(u32* __restrict__ g, u32* __restrict__ aux) {
    __shared__ u32 wsum[4];
    int tid = threadIdx.x;
    int lane = tid & 63;
    int wave = tid >> 6;
    size_t base = (size_t)blockIdx.x * 1024 + (size_t)tid * 4;
    uint4 v = *(const uint4*)(g + base);
    u32 s = v.x + v.y + v.z + v.w;
    u32 inc = s;
#pragma unroll
    for (int off = 1; off < 64; off <<= 1) {
        u32 u = __shfl_up(inc, off, 64);
        if (lane >= off) inc += u;
    }
    if (lane == 63) wsum[wave] = inc;
    __syncthreads();
    u32 woff = 0;
    for (int w = 0; w < wave; ++w) woff += wsum[w];
    u32 excl = woff + inc - s;
    uint4 o;
    o.x = excl;
    o.y = excl + v.x;
    o.z = excl + v.x + v.y;
    o.w = excl + v.x + v.y + v.z;
    *(uint4*)(g + base) = o;
    if (tid == 255) aux[blockIdx.x] = woff + inc;  // block total
}

// scatter: stable rank via wave ballot multi-split (8 ballots) + per-wave LDS histogram.
// Global bucket offset = block-local scanned ghist + wave-scanned aux prefix (fused scan_down).
__global__ __launch_bounds__(256) void scatter_kernel(const u32* __restrict__ keyin, const u32* __restrict__ valin,
                                                      u32* __restrict__ keyout, u32* __restrict__ valout,
                                                      const u32* __restrict__ ghist, const u32* __restrict__ aux,
                                                      int shift) {
    __shared__ u32 whist[4][256];
    __shared__ u32 apre[64];
    int tid = threadIdx.x;
    int lane = tid & 63;
    int wave = tid >> 6;
    // clear per-wave histograms (1024 u32, 4 per thread)
    uint4 z = {0u, 0u, 0u, 0u};
    ((uint4*)&whist[0][0])[tid] = z;
    if (tid < 64) {  // wave 0: exclusive scan of aux[64] into LDS
        u32 a = aux[tid];
        u32 inc = a;
#pragma unroll
        for (int off = 1; off < 64; off <<= 1) {
            u32 u = __shfl_up(inc, off, 64);
            if (lane >= off) inc += u;
        }
        apre[tid] = inc - a;
    }
    int gi = blockIdx.x * 256 + tid;
    u32 k = keyin[gi];
    u32 v = valin[gi];
    u32 b = (k >> shift) & 255u;
    __syncthreads();
    unsigned long long m = ~0ull;
#pragma unroll
    for (int bit = 0; bit < 8; ++bit) {
        unsigned long long bb = __ballot((int)((b >> bit) & 1u));
        m &= ((b >> bit) & 1u) ? bb : ~bb;
    }
    unsigned long long below = (lane == 0) ? 0ull : (m & ((1ull << lane) - 1ull));
    int rlane = __popcll(below);
    int cnt = __popcll(m);
    if (rlane == 0) whist[wave][b] = (u32)cnt;  // leader lane of each bucket group
    __syncthreads();
    u32 rank = (u32)rlane;
    for (int w = 0; w < wave; ++w) rank += whist[w][b];
    u32 e = b * (u32)RG + blockIdx.x;
    u32 dst = ghist[e] + apre[e >> 10] + rank;
    keyout[dst] = k;
    valout[dst] = v;
}

// ---------------- weight fp32 -> bf16 ----------------
__global__ __launch_bounds__(256) void cvt_bf16_kernel(const float* __restrict__ in, u16* __restrict__ out, int n) {
    int i = blockIdx.x * 256 + threadIdx.x;
    if (i < n) out[i] = f2bf(in[i]);
}

// ---------------- gather + positional encodings ----------------
template <bool HF32>
__global__ __launch_bounds__(256) void gather_pe_kernel(const u32* __restrict__ idx, const int* __restrict__ coords,
                                                        const float* __restrict__ feat,
                                                        const float* __restrict__ pex, const float* __restrict__ pey,
                                                        const float* __restrict__ pez, const float* __restrict__ pes,
                                                        float* __restrict__ h, u16* __restrict__ xb) {
    int row = blockIdx.x * 4 + (threadIdx.x >> 6);
    int lane = threadIdx.x & 63;
    int src = (int)idx[row];
    int cx = coords[4 * src + 1];
    int cy = coords[4 * src + 2];
    int cz = coords[4 * src + 3];
    int c = lane * 4;
    float4 f = *(const float4*)(feat + (size_t)src * DMODEL + c);
    float4 px = *(const float4*)(pex + (size_t)cx * DMODEL + c);
    float4 py = *(const float4*)(pey + (size_t)cy * DMODEL + c);
    float4 pz = *(const float4*)(pez + (size_t)cz * DMODEL + c);
    float4 ps = *(const float4*)(pes + (size_t)1 * DMODEL + c);  // pe_s[1]
    float4 r;
    r.x = f.x + px.x + py.x + pz.x + ps.x;
    r.y = f.y + px.y + py.y + pz.y + ps.y;
    r.z = f.z + px.z + py.z + pz.z + ps.z;
    r.w = f.w + px.w + py.w + pz.w + ps.w;
    if (HF32) *(float4*)(h + (size_t)row * DMODEL + c) = r;
    ushort4 o;
    o.x = f2bf(r.x);
    o.y = f2bf(r.y);
    o.z = f2bf(r.z);
    o.w = f2bf(r.w);
    *(ushort4*)(xb + (size_t)row * DMODEL + c) = o;
}

// ---------------- GEMM: C = A @ W^T + bias  (A: MxK bf16, W: OxK bf16) ----------------
// 128x128 tile, BK=64, 4 waves each computing 64x64 via 4x4 of 16x16x32 MFMA.
// Double-buffered LDS: stage(t+1) issued before compute(t); counted s_waitcnt vmcnt(8).
// LDS bank-conflict fix (T2, rule #21): global_load_lds writes linearly, so the per-lane
// GLOBAL source is pre-swizzled (16B chunk s -> s ^ (row&7)) and the ds_read slot applies
// the same XOR. Row-major [128][64]bf16 tile would otherwise be a 16-way conflict
// (16 lanes, row stride 128B, same bank); swizzle -> 2-way (free).
// Split-K via gridDim.z: slice kz computes K/KZ columns, fp32 partials to slice kz of Cout;
// bias added in slice 0 only (RELU requires gridDim.z==1).
__device__ __forceinline__ void stage_tiles(const u16* __restrict__ Abase, const u16* __restrict__ Wbase,
                                            int K, int k0, u16* la, u16* lb, int tid) {
#pragma unroll
    for (int it = 0; it < 4; ++it) {
        int cidx = tid + it * 256;   // chunk 0..1023; each chunk = 8 bf16 = 16B
        int r = cidx >> 3;           // row 0..127
        int s = cidx & 7;            // 16B slot 0..7
        int sg = s ^ (r & 7);        // inverse-swizzled source slot
        gl_lds16(Abase + (size_t)r * K + k0 + (sg << 3), la + cidx * 8);
        gl_lds16(Wbase + (size_t)r * K + k0 + (sg << 3), lb + cidx * 8);
    }
}

template <bool RELU, bool BF16OUT>
__global__ __launch_bounds__(256) void gemm_bt(const u16* __restrict__ A, const u16* __restrict__ W,
                                               const float* __restrict__ bias, void* __restrict__ Cout,
                                               int M, int O, int K) {
    __shared__ __align__(16) u16 lA[2][128 * 64];
    __shared__ __align__(16) u16 lB[2][128 * 64];
    const int tid = threadIdx.x;
    const int lane = tid & 63;
    const int wave = tid >> 6;
    const int wr = wave >> 1;
    const int wc = wave & 1;
    const int quad = lane >> 4;
    const int l16 = lane & 15;
    const int rx = l16 & 7;  // read-side XOR (row&7 == l16&7 for our row formulas)
    const int kz = blockIdx.z;
    const int Kpart = K / (int)gridDim.z;
    const size_t row0 = (size_t)blockIdx.x * 128;
    const size_t col0 = (size_t)blockIdx.y * 128;
    floatx4 acc[4][4] = {};
    const u16* Abase = A + row0 * (size_t)K + (size_t)kz * Kpart;
    const u16* Wbase = W + col0 * (size_t)K + (size_t)kz * Kpart;

    const int nt = Kpart >> 6;
    stage_tiles(Abase, Wbase, K, 0, &lA[0][0], &lB[0][0], tid);
    int buf = 0;
    for (int t = 0; t < nt; ++t) {
        if (t + 1 < nt) {
            stage_tiles(Abase, Wbase, K, (t + 1) << 6, &lA[buf ^ 1][0], &lB[buf ^ 1][0], tid);
            asm volatile("s_waitcnt vmcnt(8)" ::: "memory");  // wait current tile only
        } else {
            asm volatile("s_waitcnt vmcnt(0)" ::: "memory");
        }
        __builtin_amdgcn_s_barrier();  // all waves' stage(t) complete
        const u16* la = &lA[buf][0];
        const u16* lb = &lB[buf][0];
#pragma unroll
        for (int kk = 0; kk < 64; kk += 32) {
            short8 af[4], bf[4];
            const int sl = (kk >> 3) + quad;  // logical 16B slot 0..7
            const int so = (sl ^ rx) << 3;    // swizzled bf16 offset within row
#pragma unroll
            for (int r = 0; r < 4; ++r)
                af[r] = *(const short8*)&la[(wr * 64 + r * 16 + l16) * 64 + so];
#pragma unroll
            for (int c = 0; c < 4; ++c)
                bf[c] = *(const short8*)&lb[(wc * 64 + c * 16 + l16) * 64 + so];
#pragma unroll
            for (int r = 0; r < 4; ++r)
#pragma unroll
                for (int c = 0; c < 4; ++c)
                    acc[r][c] = __builtin_amdgcn_mfma_f32_16x16x32_bf16(af[r], bf[c], acc[r][c], 0, 0, 0);
        }
        if (t + 1 < nt) __builtin_amdgcn_s_barrier();  // reads done -> buf may be overwritten
        buf ^= 1;
    }

    float* Cf = (float*)Cout + (size_t)kz * ((size_t)M * O);  // split-K slice (fp32 path)
#pragma unroll
    for (int r = 0; r < 4; ++r) {
#pragma unroll
        for (int c = 0; c < 4; ++c) {
            size_t col = col0 + wc * 64 + c * 16 + l16;
            float bv = (kz == 0) ? bias[col] : 0.f;
#pragma unroll
            for (int reg = 0; reg < 4; ++reg) {
                size_t row = row0 + wr * 64 + r * 16 + quad * 4 + reg;
                float v = acc[r][c][reg] + bv;
                if (RELU) v = fmaxf(v, 0.f);
                if (BF16OUT)
                    ((u16*)Cout)[row * O + col] = f2bf(v);
                else
                    Cf[row * O + col] = v;
            }
        }
    }
}

// ---------------- window attention, MFMA (one block = one (window, head)) ----------------
__global__ __launch_bounds__(128) void attn_kernel(const u16* __restrict__ qkv, u16* __restrict__ outb) {
    const int wh = blockIdx.x;
    const int w = wh >> 3;   // window index within chunk
    const int h = wh & 7;
    const int tid = threadIdx.x;
    const int wave = tid >> 6;
    const int lane = tid & 63;
    const int quad = lane >> 4;
    const int l16 = lane & 15;
    __shared__ __align__(16) u16 lK[128 * KSTR];
    __shared__ __align__(16) u16 lVt[32 * VSTR];
    __shared__ __align__(16) u16 lP[128 * PSTR];
    const u16* base = qkv + (size_t)w * WSIZE * (3 * DMODEL);

    // cooperative staging: thread t handles token t
    {
        const u16* krow = base + (size_t)tid * (3 * DMODEL) + DMODEL + h * DHEAD;
        const u16* vrow = base + (size_t)tid * (3 * DMODEL) + 2 * DMODEL + h * DHEAD;
#pragma unroll
        for (int p = 0; p < 4; ++p)
            *(short8*)&lK[tid * KSTR + p * 8] = *(const short8*)(krow + p * 8);
        u16 varr[32];
#pragma unroll
        for (int p = 0; p < 4; ++p)
            *(short8*)&varr[p * 8] = *(const short8*)(vrow + p * 8);
#pragma unroll
        for (int d = 0; d < DHEAD; ++d) lVt[d * VSTR + tid] = varr[d];
    }
    // Q fragments direct from global (A-frag: row = l16 within m-tile, k = quad*8..+8)
    short8 af[4];
#pragma unroll
    for (int mi = 0; mi < 4; ++mi)
        af[mi] = *(const short8*)(base + (size_t)(wave * 64 + mi * 16 + l16) * (3 * DMODEL) + h * DHEAD + quad * 8);
    __syncthreads();

    // S = Q @ K^T : 4 m-tiles x 8 n-tiles, K-dim = 32 = one mfma step
    floatx4 acc[4][8] = {};
#pragma unroll
    for (int ni = 0; ni < 8; ++ni) {
        short8 bk = *(const short8*)&lK[(ni * 16 + l16) * KSTR + quad * 8];
#pragma unroll
        for (int mi = 0; mi < 4; ++mi)
            acc[mi][ni] = __builtin_amdgcn_mfma_f32_16x16x32_bf16(af[mi], bk, acc[mi][ni], 0, 0, 0);
    }

    // softmax over each row (row = wave*64 + mi*16 + quad*4 + reg; cols = ni*16 + l16)
    const float scale = 0.17677669529663687f;  // 1/sqrt(32)
    float inv[4][4];
#pragma unroll
    for (int mi = 0; mi < 4; ++mi) {
#pragma unroll
        for (int reg = 0; reg < 4; ++reg) {
            float m = acc[mi][0][reg];
#pragma unroll
            for (int ni = 1; ni < 8; ++ni) m = fmaxf(m, acc[mi][ni][reg]);
            m = fmaxf(m, __shfl_xor(m, 1, 64));
            m = fmaxf(m, __shfl_xor(m, 2, 64));
            m = fmaxf(m, __shfl_xor(m, 4, 64));
            m = fmaxf(m, __shfl_xor(m, 8, 64));
            float e[8];
            float sum = 0.f;
#pragma unroll
            for (int ni = 0; ni < 8; ++ni) {
                e[ni] = __expf((acc[mi][ni][reg] - m) * scale);
                sum += e[ni];
            }
            sum += __shfl_xor(sum, 1, 64);
            sum += __shfl_xor(sum, 2, 64);
            sum += __shfl_xor(sum, 4, 64);
            sum += __shfl_xor(sum, 8, 64);
            inv[mi][reg] = 1.f / sum;
            int row = wave * 64 + mi * 16 + quad * 4 + reg;
#pragma unroll
            for (int ni = 0; ni < 8; ++ni) lP[row * PSTR + ni * 16 + l16] = f2bf(e[ni]);
        }
    }
    // same-wave LDS write->read dependency (each wave reads only its own 64 rows of lP)

    // O = P @ V : 4 m-tiles x 2 n-tiles, K-dim = 128 (4 mfma steps)
    floatx4 acc2[4][2] = {};
#pragma unroll
    for (int kt = 0; kt < 4; ++kt) {
        short8 pa[4];
#pragma unroll
        for (int mi = 0; mi < 4; ++mi)
            pa[mi] = *(const short8*)&lP[(wave * 64 + mi * 16 + l16) * PSTR + kt * 32 + quad * 8];
#pragma unroll
        for (int c = 0; c < 2; ++c) {
            short8 bv = *(const short8*)&lVt[(c * 16 + l16) * VSTR + kt * 32 + quad * 8];
#pragma unroll
            for (int mi = 0; mi < 4; ++mi)
                acc2[mi][c] = __builtin_amdgcn_mfma_f32_16x16x32_bf16(pa[mi], bv, acc2[mi][c], 0, 0, 0);
        }
    }

    // epilogue: normalize and store bf16
#pragma unroll
    for (int mi = 0; mi < 4; ++mi) {
#pragma unroll
        for (int c = 0; c < 2; ++c) {
#pragma unroll
            for (int reg = 0; reg < 4; ++reg) {
                int row = wave * 64 + mi * 16 + quad * 4 + reg;
                outb[(size_t)(w * WSIZE + row) * DMODEL + h * DHEAD + c * 16 + l16] =
                    f2bf(acc2[mi][c][reg] * inv[mi][reg]);
            }
        }
    }
}

// ---------------- residual add + LayerNorm (chunk-local, pointers pre-offset) ----------------
// HF32: residual stream held in fp32 (hin/hout) vs bf16; OUTF32: fp32 output (final layer)
// NS: number of split-K delta slices to sum (slice stride dstride fp32 elems)
template <bool HF32, bool OUTF32, int NS>
__global__ __launch_bounds__(256) void resid_ln_kernel(const void* __restrict__ hin, const float* __restrict__ delta,
                                                       const float* __restrict__ g, const float* __restrict__ b,
                                                       float* __restrict__ hout, void* __restrict__ nout,
                                                       size_t dstride) {
    int row = blockIdx.x * 4 + (threadIdx.x >> 6);
    int lane = threadIdx.x & 63;
    int c = lane * 4;
    float4 x;
    if (HF32) {
        x = *(const float4*)((const float*)hin + (size_t)row * DMODEL + c);
    } else {
        ushort4 hv = *(const ushort4*)((const u16*)hin + (size_t)row * DMODEL + c);
        x.x = bf2f(hv.x);
        x.y = bf2f(hv.y);
        x.z = bf2f(hv.z);
        x.w = bf2f(hv.w);
    }
    float4 d = *(const float4*)(delta + (size_t)row * DMODEL + c);
    if (NS == 2) {
        float4 d2 = *(const float4*)(delta + dstride + (size_t)row * DMODEL + c);
        d.x += d2.x;
        d.y += d2.y;
        d.z += d2.z;
        d.w += d2.w;
    }
    x.x += d.x;
    x.y += d.y;
    x.z += d.z;
    x.w += d.w;
    float s = x.x + x.y + x.z + x.w;
#pragma unroll
    for (int off = 32; off > 0; off >>= 1) s += __shfl_xor(s, off, 64);
    float mu = s * (1.f / 256.f);
    float d0 = x.x - mu, d1 = x.y - mu, d2 = x.z - mu, d3 = x.w - mu;
    float vs = d0 * d0 + d1 * d1 + d2 * d2 + d3 * d3;
#pragma unroll
    for (int off = 32; off > 0; off >>= 1) vs += __shfl_xor(vs, off, 64);
    float rs = rsqrtf(vs * (1.f / 256.f) + LNEPS);
    float4 gg = *(const float4*)(g + c);
    float4 bb = *(const float4*)(b + c);
    float4 y;
    y.x = d0 * rs * gg.x + bb.x;
    y.y = d1 * rs * gg.y + bb.y;
    y.z = d2 * rs * gg.z + bb.z;
    y.w = d3 * rs * gg.w + bb.w;
    if (HF32) *(float4*)(hout + (size_t)row * DMODEL + c) = y;
    if (OUTF32) {
        *(float4*)((float*)nout + (size_t)row * DMODEL + c) = y;
    } else {
        ushort4 o;
        o.x = f2bf(y.x);
        o.y = f2bf(y.y);
        o.z = f2bf(y.z);
        o.w = f2bf(y.w);
        *(ushort4*)((u16*)nout + (size_t)row * DMODEL + c) = o;
    }
}

// ---------------- launch ----------------
extern "C" void kernel_launch(void* const* d_in, const int* in_sizes, int n_in,
                              void* d_out, int out_size, void* d_ws, size_t ws_size,
                              hipStream_t stream) {
    (void)in_sizes;
    (void)n_in;
    (void)out_size;
    const int* coords = (const int*)d_in[0];
    const float* feat = (const float*)d_in[1];
    const float* pex = (const float*)d_in[2];
    const float* pey = (const float*)d_in[3];
    const float* pez = (const float*)d_in[4];
    const float* pes = (const float*)d_in[5];
    const float* Wqkv = (const float*)d_in[6];
    const float* bqkv = (const float*)d_in[7];
    const float* Wo = (const float*)d_in[8];
    const float* bo = (const float*)d_in[9];
    const float* W1 = (const float*)d_in[10];
    const float* b1 = (const float*)d_in[11];
    const float* W2 = (const float*)d_in[12];
    const float* b2 = (const float*)d_in[13];
    const float* g1 = (const float*)d_in[14];
    const float* be1 = (const float*)d_in[15];
    const float* g2 = (const float*)d_in[16];
    const float* be2 = (const float*)d_in[17];

    auto al = [](size_t x) { return (x + 255) & ~(size_t)255; };
    // fixed allocations
    const size_t sortB = 4 * al((size_t)NPTS * 4) + al((size_t)256 * RG * 4) + 256;
    const size_t wqkvB = al((size_t)NLAYER * 3 * DMODEL * DMODEL * 2);
    const size_t woB = al((size_t)NLAYER * DMODEL * DMODEL * 2);
    const size_t w1B = al((size_t)NLAYER * FFDIM * DMODEL * 2);
    const size_t w2B = al((size_t)NLAYER * DMODEL * FFDIM * 2);
    const size_t wB = wqkvB + woB + w1B + w2B;
    const size_t xbB = al((size_t)NPTS * DMODEL * 2);
    const size_t hB = al((size_t)NPTS * DMODEL * 4);

    // choose mode + chunk size + split-K to fit ws_size.
    // Priority: larger CH (fewer dispatches) > split-K=2 for W2 (grid parallelism on K).
    int CH = 0, KSP = 1;
    bool modeA = true;
    for (int ch = 65536; ch >= 128 && !CH; ch >>= 1) {
        for (int ksp = 2; ksp >= 1; --ksp) {
            size_t need = sortB + wB + xbB + hB + al((size_t)ch * 4096) + al((size_t)ch * 1024 * ksp) + 65536;
            if (need <= ws_size) { CH = ch; KSP = ksp; modeA = true; break; }
        }
    }
    if (!CH) {
        for (int ch = 65536; ch >= 128 && !CH; ch >>= 1) {
            for (int ksp = 2; ksp >= 1; --ksp) {
                size_t need = sortB + wB + xbB + al((size_t)ch * 4096) + al((size_t)ch * 1024 * ksp) + 65536;
                if (need <= ws_size) { CH = ch; KSP = ksp; modeA = false; break; }
            }
        }
    }
    if (!CH) { CH = 128; KSP = 1; modeA = false; }  // nothing fits; best effort

    char* ws = (char*)d_ws;
    size_t off = 0;
    auto alloc = [&](size_t bytes) -> void* {
        void* p = ws + off;
        off += al(bytes);
        return p;
    };
    u32* key0 = (u32*)alloc(NPTS * 4);
    u32* val0 = (u32*)alloc(NPTS * 4);
    u32* key1 = (u32*)alloc(NPTS * 4);
    u32* val1 = (u32*)alloc(NPTS * 4);
    u32* ghist = (u32*)alloc(256 * RG * 4);
    u32* aux = (u32*)alloc(64 * 4);
    u16* wqkv_b = (u16*)alloc((size_t)NLAYER * 3 * DMODEL * DMODEL * 2);
    u16* wo_b = (u16*)alloc((size_t)NLAYER * DMODEL * DMODEL * 2);
    u16* w1_b = (u16*)alloc((size_t)NLAYER * FFDIM * DMODEL * 2);
    u16* w2_b = (u16*)alloc((size_t)NLAYER * DMODEL * FFDIM * 2);
    u16* xb = (u16*)alloc((size_t)NPTS * DMODEL * 2);
    float* h = modeA ? (float*)alloc((size_t)NPTS * DMODEL * 4) : nullptr;
    u16* scratch1 = (u16*)alloc((size_t)CH * 4096);  // qkv (CH*768) + attout (CH*256) | ffn-mid (CH*2048)
    float* tmpc = (float*)alloc((size_t)CH * 1024 * KSP);  // KSP x (CH x 256) fp32 delta slices
    const size_t dstride = (size_t)CH * DMODEL;  // fp32 elems per slice

    // 1. morton keys
    morton_kernel<<<NPTS / 256, 256, 0, stream>>>(coords, key0, val0);

    // 2. stable radix sort, 3 x 8-bit passes (24-bit keys)
    u32 *ki = key0, *vi = val0, *ko = key1, *vo = val1;
    for (int p = 0; p < 3; ++p) {
        hist_kernel<<<RG, 256, 0, stream>>>(ki, ghist, p * 8);
        scan_up<<<64, 256, 0, stream>>>(ghist, aux);
        scatter_kernel<<<RG, 256, 0, stream>>>(ki, vi, ko, vo, ghist, aux, p * 8);
        u32* t;
        t = ki; ki = ko; ko = t;
        t = vi; vi = vo; vo = t;
    }
    const u32* idx = vi;  // sorted original indices

    // 3. weights -> bf16
    cvt_bf16_kernel<<<(NLAYER * 3 * DMODEL * DMODEL) / 256, 256, 0, stream>>>(Wqkv, wqkv_b, NLAYER * 3 * DMODEL * DMODEL);
    cvt_bf16_kernel<<<(NLAYER * DMODEL * DMODEL) / 256, 256, 0, stream>>>(Wo, wo_b, NLAYER * DMODEL * DMODEL);
    cvt_bf16_kernel<<<(NLAYER * FFDIM * DMODEL) / 256, 256, 0, stream>>>(W1, w1_b, NLAYER * FFDIM * DMODEL);
    cvt_bf16_kernel<<<(NLAYER * DMODEL * FFDIM) / 256, 256, 0, stream>>>(W2, w2_b, NLAYER * DMODEL * FFDIM);

    // 4. gather + PE
    if (modeA)
        gather_pe_kernel<true><<<NPTS / 4, 256, 0, stream>>>(idx, coords, feat, pex, pey, pez, pes, h, xb);
    else
        gather_pe_kernel<false><<<NPTS / 4, 256, 0, stream>>>(idx, coords, feat, pex, pey, pez, pes, nullptr, xb);

    // 5. encoder layers, chunked over rows (CH rows = CH/128 windows per chunk)
    const int nch = NPTS / CH;
    u16* qkvc = scratch1;                     // CH x 768 bf16
    u16* attoutc = scratch1 + (size_t)CH * 768;  // CH x 256 bf16
    u16* midc = scratch1;                     // CH x 2048 bf16 (reuses qkv region)
    for (int l = 0; l < NLAYER; ++l) {
        for (int c = 0; c < nch; ++c) {
            u16* xc = xb + (size_t)c * CH * DMODEL;
            float* hc = modeA ? h + (size_t)c * CH * DMODEL : nullptr;
            // qkv = x @ Wqkv^T + bqkv  -> bf16
            gemm_bt<false, true><<<dim3(CH / 128, (3 * DMODEL) / 128), 256, 0, stream>>>(
                xc, wqkv_b + (size_t)l * 3 * DMODEL * DMODEL, bqkv + (size_t)l * 3 * DMODEL, qkvc,
                CH, 3 * DMODEL, DMODEL);
            // window attention (MFMA) -> attout bf16
            attn_kernel<<<(CH / WSIZE) * NHEAD, 128, 0, stream>>>(qkvc, attoutc);
            // o = attout @ Wo^T + bo -> fp32
            gemm_bt<false, false><<<dim3(CH / 128, DMODEL / 128), 256, 0, stream>>>(
                attoutc, wo_b + (size_t)l * DMODEL * DMODEL, bo + (size_t)l * DMODEL, tmpc,
                CH, DMODEL, DMODEL);
            // h = LN(h + o)
            if (modeA)
                resid_ln_kernel<true, false, 1><<<CH / 4, 256, 0, stream>>>(hc, tmpc, g1 + (size_t)l * DMODEL,
                                                                            be1 + (size_t)l * DMODEL, hc, xc, dstride);
            else
                resid_ln_kernel<false, false, 1><<<CH / 4, 256, 0, stream>>>(xc, tmpc, g1 + (size_t)l * DMODEL,
                                                                             be1 + (size_t)l * DMODEL, nullptr, xc, dstride);
            // FFN
            gemm_bt<true, true><<<dim3(CH / 128, FFDIM / 128), 256, 0, stream>>>(
                xc, w1_b + (size_t)l * FFDIM * DMODEL, b1 + (size_t)l * FFDIM, midc,
                CH, FFDIM, DMODEL);
            gemm_bt<false, false><<<dim3(CH / 128, DMODEL / 128, KSP), 256, 0, stream>>>(
                midc, w2_b + (size_t)l * DMODEL * FFDIM, b2 + (size_t)l * DMODEL, tmpc,
                CH, DMODEL, FFDIM);
            // h = LN(h + ff)
            bool last = (l == NLAYER - 1);
            void* outc = last ? (void*)((float*)d_out + (size_t)c * CH * DMODEL) : (void*)xc;
            if (modeA) {
                if (last) {
                    if (KSP == 2)
                        resid_ln_kernel<true, true, 2><<<CH / 4, 256, 0, stream>>>(hc, tmpc, g2 + (size_t)l * DMODEL,
                                                                                   be2 + (size_t)l * DMODEL, hc, outc, dstride);
                    else
                        resid_ln_kernel<true, true, 1><<<CH / 4, 256, 0, stream>>>(hc, tmpc, g2 + (size_t)l * DMODEL,
                                                                                   be2 + (size_t)l * DMODEL, hc, outc, dstride);
                } else {
                    if (KSP == 2)
                        resid_ln_kernel<true, false, 2><<<CH / 4, 256, 0, stream>>>(hc, tmpc, g2 + (size_t)l * DMODEL,
                                                                                    be2 + (size_t)l * DMODEL, hc, outc, dstride);
                    else
                        resid_ln_kernel<true, false, 1><<<CH / 4, 256, 0, stream>>>(hc, tmpc, g2 + (size_t)l * DMODEL,
                                                                                    be2 + (size_t)l * DMODEL, hc, outc, dstride);
                }
            } else {
                if (last) {
                    if (KSP == 2)
                        resid_ln_kernel<false, true, 2><<<CH / 4, 256, 0, stream>>>(xc, tmpc, g2 + (size_t)l * DMODEL,
                                                                                    be2 + (size_t)l * DMODEL, nullptr, outc, dstride);
                    else
                        resid_ln_kernel<false, true, 1><<<CH / 4, 256, 0, stream>>>(xc, tmpc, g2 + (size_t)l * DMODEL,
                                                                                    be2 + (size_t)l * DMODEL, nullptr, outc, dstride);
                } else {
                    if (KSP == 2)
                        resid_ln_kernel<false, false, 2><<<CH / 4, 256, 0, stream>>>(xc, tmpc, g2 + (size_t)l * DMODEL,
                                                                                     be2 + (size_t)l * DMODEL, nullptr, outc, dstride);
                    else
                        resid_ln_kernel<false, false, 1><<<CH / 4, 256, 0, stream>>>(xc, tmpc, g2 + (size_t)l * DMODEL,
                                                                                     be2 + (size_t)l * DMODEL, nullptr, outc, dstride);
                }
            }
        }
    }
}

// Round 5
// 2387.852 us; speedup vs baseline: 1.1300x; 1.0536x over previous
//
#include <hip/hip_runtime.h>

typedef unsigned int u32;
typedef unsigned short u16;

#define NPTS 65536
#define DMODEL 256
#define NHEAD 8
#define DHEAD 32
#define NLAYER 4
#define FFDIM 2048
#define WSIZE 128
#define LNEPS 1e-5f
#define RG 256  // radix sort blocks (chunk = 256 elements each)

// LDS strides (bf16 elems) chosen to avoid systematic bank conflicts
#define KSTR 36
#define VSTR 132
#define PSTR 132

typedef __attribute__((ext_vector_type(8))) short short8;
typedef __attribute__((ext_vector_type(4))) float floatx4;

__device__ __forceinline__ float bf2f(u16 v) {
    u32 u = ((u32)v) << 16;
    float f;
    __builtin_memcpy(&f, &u, 4);
    return f;
}
__device__ __forceinline__ u16 f2bf(float f) {
    u32 u;
    __builtin_memcpy(&u, &f, 4);
    u32 r = (u + 0x7fffu + ((u >> 16) & 1u)) >> 16;
    return (u16)r;
}

__device__ __forceinline__ void gl_lds16(const void* g, void* l) {
    __builtin_amdgcn_global_load_lds((const __attribute__((address_space(1))) u32*)g,
                                     (__attribute__((address_space(3))) u32*)l, 16, 0, 0);
}

// ---------------- Morton keys ----------------
__global__ __launch_bounds__(256) void morton_kernel(const int* __restrict__ coords,
                                                     u32* __restrict__ key, u32* __restrict__ val) {
    int i = blockIdx.x * 256 + threadIdx.x;
    int b = coords[4 * i + 0];
    int x = coords[4 * i + 1];
    int y = coords[4 * i + 2];
    int z = coords[4 * i + 3];
    u32 m = 0;
#pragma unroll
    for (int t = 0; t < 7; ++t) {
        m |= ((u32)((x >> t) & 1) << (3 * t + 2)) | ((u32)((y >> t) & 1) << (3 * t + 1)) |
             ((u32)((z >> t) & 1) << (3 * t));
    }
    key[i] = ((u32)b << 21) | m;
    val[i] = (u32)i;
}

// ---------------- radix sort (stable LSD, 3 x 8-bit) ----------------
__global__ __launch_bounds__(256) void hist_kernel(const u32* __restrict__ key, u32* __restrict__ ghist,
                                                   int shift) {
    __shared__ u32 h[256];
    int tid = threadIdx.x;
    h[tid] = 0;
    __syncthreads();
    u32 k = key[blockIdx.x * 256 + tid];
    atomicAdd(&h[(k >> shift) & 255u], 1u);
    __syncthreads();
    ghist[(size_t)tid * RG + blockIdx.x] = h[tid];  // bucket-major
}

// parallel exclusive scan over 256*RG = 65536 entries:
// scan_up: 64 blocks x 1024 entries (256 thr x uint4) -> in-place block-local
//          exclusive scan + block total to aux[64]
// (aux prefix is folded into scatter_kernel; no scan_down pass)
__global__ __launch_bounds__(256) void scan_up(u32* __restrict__ g, u32* __restrict__ aux) {
    __shared__ u32 wsum[4];
    int tid = threadIdx.x;
    int lane = tid & 63;
    int wave = tid >> 6;
    size_t base = (size_t)blockIdx.x * 1024 + (size_t)tid * 4;
    uint4 v = *(const uint4*)(g + base);
    u32 s = v.x + v.y + v.z + v.w;
    u32 inc = s;
#pragma unroll
    for (int off = 1; off < 64; off <<= 1) {
        u32 u = __shfl_up(inc, off, 64);
        if (lane >= off) inc += u;
    }
    if (lane == 63) wsum[wave] = inc;
    __syncthreads();
    u32 woff = 0;
    for (int w = 0; w < wave; ++w) woff += wsum[w];
    u32 excl = woff + inc - s;
    uint4 o;
    o.x = excl;
    o.y = excl + v.x;
    o.z = excl + v.x + v.y;
    o.w = excl + v.x + v.y + v.z;
    *(uint4*)(g + base) = o;
    if (tid == 255) aux[blockIdx.x] = woff + inc;  // block total
}

// scatter: stable rank via wave ballot multi-split (8 ballots) + per-wave LDS histogram.
// Global bucket offset = block-local scanned ghist + wave-scanned aux prefix (fused scan_down).
__global__ __launch_bounds__(256) void scatter_kernel(const u32* __restrict__ keyin, const u32* __restrict__ valin,
                                                      u32* __restrict__ keyout, u32* __restrict__ valout,
                                                      const u32* __restrict__ ghist, const u32* __restrict__ aux,
                                                      int shift) {
    __shared__ u32 whist[4][256];
    __shared__ u32 apre[64];
    int tid = threadIdx.x;
    int lane = tid & 63;
    int wave = tid >> 6;
    // clear per-wave histograms (1024 u32, 4 per thread)
    uint4 z = {0u, 0u, 0u, 0u};
    ((uint4*)&whist[0][0])[tid] = z;
    if (tid < 64) {  // wave 0: exclusive scan of aux[64] into LDS
        u32 a = aux[tid];
        u32 inc = a;
#pragma unroll
        for (int off = 1; off < 64; off <<= 1) {
            u32 u = __shfl_up(inc, off, 64);
            if (lane >= off) inc += u;
        }
        apre[tid] = inc - a;
    }
    int gi = blockIdx.x * 256 + tid;
    u32 k = keyin[gi];
    u32 v = valin[gi];
    u32 b = (k >> shift) & 255u;
    __syncthreads();
    unsigned long long m = ~0ull;
#pragma unroll
    for (int bit = 0; bit < 8; ++bit) {
        unsigned long long bb = __ballot((int)((b >> bit) & 1u));
        m &= ((b >> bit) & 1u) ? bb : ~bb;
    }
    unsigned long long below = (lane == 0) ? 0ull : (m & ((1ull << lane) - 1ull));
    int rlane = __popcll(below);
    int cnt = __popcll(m);
    if (rlane == 0) whist[wave][b] = (u32)cnt;  // leader lane of each bucket group
    __syncthreads();
    u32 rank = (u32)rlane;
    for (int w = 0; w < wave; ++w) rank += whist[w][b];
    u32 e = b * (u32)RG + blockIdx.x;
    u32 dst = ghist[e] + apre[e >> 10] + rank;
    keyout[dst] = k;
    valout[dst] = v;
}

// ---------------- weight fp32 -> bf16 ----------------
__global__ __launch_bounds__(256) void cvt_bf16_kernel(const float* __restrict__ in, u16* __restrict__ out, int n) {
    int i = blockIdx.x * 256 + threadIdx.x;
    if (i < n) out[i] = f2bf(in[i]);
}

// ---------------- gather + positional encodings ----------------
template <bool HF32>
__global__ __launch_bounds__(256) void gather_pe_kernel(const u32* __restrict__ idx, const int* __restrict__ coords,
                                                        const float* __restrict__ feat,
                                                        const float* __restrict__ pex, const float* __restrict__ pey,
                                                        const float* __restrict__ pez, const float* __restrict__ pes,
                                                        float* __restrict__ h, u16* __restrict__ xb) {
    int row = blockIdx.x * 4 + (threadIdx.x >> 6);
    int lane = threadIdx.x & 63;
    int src = (int)idx[row];
    int cx = coords[4 * src + 1];
    int cy = coords[4 * src + 2];
    int cz = coords[4 * src + 3];
    int c = lane * 4;
    float4 f = *(const float4*)(feat + (size_t)src * DMODEL + c);
    float4 px = *(const float4*)(pex + (size_t)cx * DMODEL + c);
    float4 py = *(const float4*)(pey + (size_t)cy * DMODEL + c);
    float4 pz = *(const float4*)(pez + (size_t)cz * DMODEL + c);
    float4 ps = *(const float4*)(pes + (size_t)1 * DMODEL + c);  // pe_s[1]
    float4 r;
    r.x = f.x + px.x + py.x + pz.x + ps.x;
    r.y = f.y + px.y + py.y + pz.y + ps.y;
    r.z = f.z + px.z + py.z + pz.z + ps.z;
    r.w = f.w + px.w + py.w + pz.w + ps.w;
    if (HF32) *(float4*)(h + (size_t)row * DMODEL + c) = r;
    ushort4 o;
    o.x = f2bf(r.x);
    o.y = f2bf(r.y);
    o.z = f2bf(r.z);
    o.w = f2bf(r.w);
    *(ushort4*)(xb + (size_t)row * DMODEL + c) = o;
}

// ---------------- GEMM: C = A @ W^T + bias  (A: MxK bf16, W: OxK bf16) ----------------
// 128x128 tile, BK=32, 4 waves each computing 64x64 via 4x4 of 16x16x32 MFMA (1 step/tile).
// BK=32 keeps LDS at 2x8KBx2 = 32 KB -> 5 blocks/CU resident (vs 2 at BK=64): the kernel
// is latency-bound (all counters low), so TLP is the lever. Double-buffered, counted
// s_waitcnt vmcnt(4) (next tile's 4 loads stay in flight across the barrier).
// Bank-conflict swizzle (T2, rule #21): row stride is 64B, so 16 lanes reading one 16B
// slot would 8-way conflict; source chunk s -> s ^ ((row>>1)&3) (global side) + same XOR
// on the ds_read slot spreads 16 lanes over 8 bank-quads = 2-way (free). Chunk1 (row+64)
// has the same XOR since bit 1,2 of row are unchanged -> single base pointer + row stride.
// Split-K via gridDim.z: slice kz computes K/KZ cols, fp32 partials to slice kz of Cout;
// bias in slice 0 only (RELU requires gridDim.z==1).
template <bool RELU, bool BF16OUT>
__global__ __launch_bounds__(256, 5) void gemm_bt(const u16* __restrict__ A, const u16* __restrict__ W,
                                                  const float* __restrict__ bias, void* __restrict__ Cout,
                                                  int M, int O, int K) {
    __shared__ __align__(16) u16 lA[2 * 128 * 32];
    __shared__ __align__(16) u16 lB[2 * 128 * 32];
    const int tid = threadIdx.x;
    const int lane = tid & 63;
    const int wave = tid >> 6;
    const int wr = wave >> 1;
    const int wc = wave & 1;
    const int quad = lane >> 4;
    const int l16 = lane & 15;
    const int kz = blockIdx.z;
    const int Kpart = K / (int)gridDim.z;
    const size_t row0 = (size_t)blockIdx.x * 128;
    const size_t col0 = (size_t)blockIdx.y * 128;
    floatx4 acc[4][4] = {};

    // staging: thread handles chunks {tid, tid+256}; chunk c: row=c>>2, slot=c&3
    const int r0 = tid >> 2;
    const int sg0 = (tid & 3) ^ ((r0 >> 1) & 3);  // inverse-swizzled source slot
    const u16* pA = A + (row0 + r0) * (size_t)K + (size_t)kz * Kpart + (sg0 << 3);
    const u16* pW = W + (col0 + r0) * (size_t)K + (size_t)kz * Kpart + (sg0 << 3);
    const size_t rstep = (size_t)64 * K;  // chunk1 = row+64, same slot swizzle
    const int oA = tid * 8;               // lds elem offset of chunk0 (chunk1 at +2048)

    const int nt = Kpart >> 5;
    // prologue: stage tile 0 -> buf 0
    gl_lds16(pA, lA + oA);
    gl_lds16(pA + rstep, lA + oA + 2048);
    gl_lds16(pW, lB + oA);
    gl_lds16(pW + rstep, lB + oA + 2048);
    pA += 32;
    pW += 32;

    const int sx = (quad ^ ((l16 >> 1) & 3)) << 3;  // read-side swizzled slot offset
    const int rdA = (wr * 64 + l16) * 32 + sx;
    const int rdB = (wc * 64 + l16) * 32 + sx;
    int buf = 0;
    for (int t = 0; t < nt; ++t) {
        if (t + 1 < nt) {
            const int nb = (buf ^ 1) * 4096;
            gl_lds16(pA, lA + nb + oA);
            gl_lds16(pA + rstep, lA + nb + oA + 2048);
            gl_lds16(pW, lB + nb + oA);
            gl_lds16(pW + rstep, lB + nb + oA + 2048);
            pA += 32;
            pW += 32;
            asm volatile("s_waitcnt vmcnt(4)" ::: "memory");  // current tile landed; next stays in flight
        } else {
            asm volatile("s_waitcnt vmcnt(0)" ::: "memory");
        }
        __builtin_amdgcn_s_barrier();  // all waves' stage(t) complete
        const u16* la = lA + buf * 4096 + rdA;
        const u16* lb = lB + buf * 4096 + rdB;
        short8 af[4], bf[4];
#pragma unroll
        for (int r = 0; r < 4; ++r) af[r] = *(const short8*)(la + r * 512);
#pragma unroll
        for (int c = 0; c < 4; ++c) bf[c] = *(const short8*)(lb + c * 512);
#pragma unroll
        for (int r = 0; r < 4; ++r)
#pragma unroll
            for (int c = 0; c < 4; ++c)
                acc[r][c] = __builtin_amdgcn_mfma_f32_16x16x32_bf16(af[r], bf[c], acc[r][c], 0, 0, 0);
        if (t + 1 < nt) __builtin_amdgcn_s_barrier();  // reads done -> other buf may be overwritten
        buf ^= 1;
    }

    float* Cf = (float*)Cout + (size_t)kz * ((size_t)M * O);  // split-K slice (fp32 path)
#pragma unroll
    for (int r = 0; r < 4; ++r) {
#pragma unroll
        for (int c = 0; c < 4; ++c) {
            size_t col = col0 + wc * 64 + c * 16 + l16;
            float bv = (kz == 0) ? bias[col] : 0.f;
#pragma unroll
            for (int reg = 0; reg < 4; ++reg) {
                size_t row = row0 + wr * 64 + r * 16 + quad * 4 + reg;
                float v = acc[r][c][reg] + bv;
                if (RELU) v = fmaxf(v, 0.f);
                if (BF16OUT)
                    ((u16*)Cout)[row * O + col] = f2bf(v);
                else
                    Cf[row * O + col] = v;
            }
        }
    }
}

// ---------------- window attention, MFMA (one block = one (window, head)) ----------------
__global__ __launch_bounds__(128) void attn_kernel(const u16* __restrict__ qkv, u16* __restrict__ outb) {
    const int wh = blockIdx.x;
    const int w = wh >> 3;   // window index within chunk
    const int h = wh & 7;
    const int tid = threadIdx.x;
    const int wave = tid >> 6;
    const int lane = tid & 63;
    const int quad = lane >> 4;
    const int l16 = lane & 15;
    __shared__ __align__(16) u16 lK[128 * KSTR];
    __shared__ __align__(16) u16 lVt[32 * VSTR];
    __shared__ __align__(16) u16 lP[128 * PSTR];
    const u16* base = qkv + (size_t)w * WSIZE * (3 * DMODEL);

    // cooperative staging: thread t handles token t
    {
        const u16* krow = base + (size_t)tid * (3 * DMODEL) + DMODEL + h * DHEAD;
        const u16* vrow = base + (size_t)tid * (3 * DMODEL) + 2 * DMODEL + h * DHEAD;
#pragma unroll
        for (int p = 0; p < 4; ++p)
            *(short8*)&lK[tid * KSTR + p * 8] = *(const short8*)(krow + p * 8);
        u16 varr[32];
#pragma unroll
        for (int p = 0; p < 4; ++p)
            *(short8*)&varr[p * 8] = *(const short8*)(vrow + p * 8);
#pragma unroll
        for (int d = 0; d < DHEAD; ++d) lVt[d * VSTR + tid] = varr[d];
    }
    // Q fragments direct from global (A-frag: row = l16 within m-tile, k = quad*8..+8)
    short8 af[4];
#pragma unroll
    for (int mi = 0; mi < 4; ++mi)
        af[mi] = *(const short8*)(base + (size_t)(wave * 64 + mi * 16 + l16) * (3 * DMODEL) + h * DHEAD + quad * 8);
    __syncthreads();

    // S = Q @ K^T : 4 m-tiles x 8 n-tiles, K-dim = 32 = one mfma step
    floatx4 acc[4][8] = {};
#pragma unroll
    for (int ni = 0; ni < 8; ++ni) {
        short8 bk = *(const short8*)&lK[(ni * 16 + l16) * KSTR + quad * 8];
#pragma unroll
        for (int mi = 0; mi < 4; ++mi)
            acc[mi][ni] = __builtin_amdgcn_mfma_f32_16x16x32_bf16(af[mi], bk, acc[mi][ni], 0, 0, 0);
    }

    // softmax over each row (row = wave*64 + mi*16 + quad*4 + reg; cols = ni*16 + l16)
    const float scale = 0.17677669529663687f;  // 1/sqrt(32)
    float inv[4][4];
#pragma unroll
    for (int mi = 0; mi < 4; ++mi) {
#pragma unroll
        for (int reg = 0; reg < 4; ++reg) {
            float m = acc[mi][0][reg];
#pragma unroll
            for (int ni = 1; ni < 8; ++ni) m = fmaxf(m, acc[mi][ni][reg]);
            m = fmaxf(m, __shfl_xor(m, 1, 64));
            m = fmaxf(m, __shfl_xor(m, 2, 64));
            m = fmaxf(m, __shfl_xor(m, 4, 64));
            m = fmaxf(m, __shfl_xor(m, 8, 64));
            float e[8];
            float sum = 0.f;
#pragma unroll
            for (int ni = 0; ni < 8; ++ni) {
                e[ni] = __expf((acc[mi][ni][reg] - m) * scale);
                sum += e[ni];
            }
            sum += __shfl_xor(sum, 1, 64);
            sum += __shfl_xor(sum, 2, 64);
            sum += __shfl_xor(sum, 4, 64);
            sum += __shfl_xor(sum, 8, 64);
            inv[mi][reg] = 1.f / sum;
            int row = wave * 64 + mi * 16 + quad * 4 + reg;
#pragma unroll
            for (int ni = 0; ni < 8; ++ni) lP[row * PSTR + ni * 16 + l16] = f2bf(e[ni]);
        }
    }
    // same-wave LDS write->read dependency (each wave reads only its own 64 rows of lP)

    // O = P @ V : 4 m-tiles x 2 n-tiles, K-dim = 128 (4 mfma steps)
    floatx4 acc2[4][2] = {};
#pragma unroll
    for (int kt = 0; kt < 4; ++kt) {
        short8 pa[4];
#pragma unroll
        for (int mi = 0; mi < 4; ++mi)
            pa[mi] = *(const short8*)&lP[(wave * 64 + mi * 16 + l16) * PSTR + kt * 32 + quad * 8];
#pragma unroll
        for (int c = 0; c < 2; ++c) {
            short8 bv = *(const short8*)&lVt[(c * 16 + l16) * VSTR + kt * 32 + quad * 8];
#pragma unroll
            for (int mi = 0; mi < 4; ++mi)
                acc2[mi][c] = __builtin_amdgcn_mfma_f32_16x16x32_bf16(pa[mi], bv, acc2[mi][c], 0, 0, 0);
        }
    }

    // epilogue: normalize and store bf16
#pragma unroll
    for (int mi = 0; mi < 4; ++mi) {
#pragma unroll
        for (int c = 0; c < 2; ++c) {
#pragma unroll
            for (int reg = 0; reg < 4; ++reg) {
                int row = wave * 64 + mi * 16 + quad * 4 + reg;
                outb[(size_t)(w * WSIZE + row) * DMODEL + h * DHEAD + c * 16 + l16] =
                    f2bf(acc2[mi][c][reg] * inv[mi][reg]);
            }
        }
    }
}

// ---------------- residual add + LayerNorm (chunk-local, pointers pre-offset) ----------------
// HF32: residual stream held in fp32 (hin/hout) vs bf16; OUTF32: fp32 output (final layer)
// NS: number of split-K delta slices to sum (slice stride dstride fp32 elems)
template <bool HF32, bool OUTF32, int NS>
__global__ __launch_bounds__(256) void resid_ln_kernel(const void* __restrict__ hin, const float* __restrict__ delta,
                                                       const float* __restrict__ g, const float* __restrict__ b,
                                                       float* __restrict__ hout, void* __restrict__ nout,
                                                       size_t dstride) {
    int row = blockIdx.x * 4 + (threadIdx.x >> 6);
    int lane = threadIdx.x & 63;
    int c = lane * 4;
    float4 x;
    if (HF32) {
        x = *(const float4*)((const float*)hin + (size_t)row * DMODEL + c);
    } else {
        ushort4 hv = *(const ushort4*)((const u16*)hin + (size_t)row * DMODEL + c);
        x.x = bf2f(hv.x);
        x.y = bf2f(hv.y);
        x.z = bf2f(hv.z);
        x.w = bf2f(hv.w);
    }
    float4 d = *(const float4*)(delta + (size_t)row * DMODEL + c);
    if (NS == 2) {
        float4 d2 = *(const float4*)(delta + dstride + (size_t)row * DMODEL + c);
        d.x += d2.x;
        d.y += d2.y;
        d.z += d2.z;
        d.w += d2.w;
    }
    x.x += d.x;
    x.y += d.y;
    x.z += d.z;
    x.w += d.w;
    float s = x.x + x.y + x.z + x.w;
#pragma unroll
    for (int off = 32; off > 0; off >>= 1) s += __shfl_xor(s, off, 64);
    float mu = s * (1.f / 256.f);
    float d0 = x.x - mu, d1 = x.y - mu, d2 = x.z - mu, d3 = x.w - mu;
    float vs = d0 * d0 + d1 * d1 + d2 * d2 + d3 * d3;
#pragma unroll
    for (int off = 32; off > 0; off >>= 1) vs += __shfl_xor(vs, off, 64);
    float rs = rsqrtf(vs * (1.f / 256.f) + LNEPS);
    float4 gg = *(const float4*)(g + c);
    float4 bb = *(const float4*)(b + c);
    float4 y;
    y.x = d0 * rs * gg.x + bb.x;
    y.y = d1 * rs * gg.y + bb.y;
    y.z = d2 * rs * gg.z + bb.z;
    y.w = d3 * rs * gg.w + bb.w;
    if (HF32) *(float4*)(hout + (size_t)row * DMODEL + c) = y;
    if (OUTF32) {
        *(float4*)((float*)nout + (size_t)row * DMODEL + c) = y;
    } else {
        ushort4 o;
        o.x = f2bf(y.x);
        o.y = f2bf(y.y);
        o.z = f2bf(y.z);
        o.w = f2bf(y.w);
        *(ushort4*)((u16*)nout + (size_t)row * DMODEL + c) = o;
    }
}

// ---------------- launch ----------------
extern "C" void kernel_launch(void* const* d_in, const int* in_sizes, int n_in,
                              void* d_out, int out_size, void* d_ws, size_t ws_size,
                              hipStream_t stream) {
    (void)in_sizes;
    (void)n_in;
    (void)out_size;
    const int* coords = (const int*)d_in[0];
    const float* feat = (const float*)d_in[1];
    const float* pex = (const float*)d_in[2];
    const float* pey = (const float*)d_in[3];
    const float* pez = (const float*)d_in[4];
    const float* pes = (const float*)d_in[5];
    const float* Wqkv = (const float*)d_in[6];
    const float* bqkv = (const float*)d_in[7];
    const float* Wo = (const float*)d_in[8];
    const float* bo = (const float*)d_in[9];
    const float* W1 = (const float*)d_in[10];
    const float* b1 = (const float*)d_in[11];
    const float* W2 = (const float*)d_in[12];
    const float* b2 = (const float*)d_in[13];
    const float* g1 = (const float*)d_in[14];
    const float* be1 = (const float*)d_in[15];
    const float* g2 = (const float*)d_in[16];
    const float* be2 = (const float*)d_in[17];

    auto al = [](size_t x) { return (x + 255) & ~(size_t)255; };
    // fixed allocations
    const size_t sortB = 4 * al((size_t)NPTS * 4) + al((size_t)256 * RG * 4) + 256;
    const size_t wqkvB = al((size_t)NLAYER * 3 * DMODEL * DMODEL * 2);
    const size_t woB = al((size_t)NLAYER * DMODEL * DMODEL * 2);
    const size_t w1B = al((size_t)NLAYER * FFDIM * DMODEL * 2);
    const size_t w2B = al((size_t)NLAYER * DMODEL * FFDIM * 2);
    const size_t wB = wqkvB + woB + w1B + w2B;
    const size_t xbB = al((size_t)NPTS * DMODEL * 2);
    const size_t hB = al((size_t)NPTS * DMODEL * 4);

    // choose mode + chunk size + split-K to fit ws_size.
    // Priority: larger CH (fewer dispatches) > split-K=2 for W2 (grid parallelism on K).
    int CH = 0, KSP = 1;
    bool modeA = true;
    for (int ch = 65536; ch >= 128 && !CH; ch >>= 1) {
        for (int ksp = 2; ksp >= 1; --ksp) {
            size_t need = sortB + wB + xbB + hB + al((size_t)ch * 4096) + al((size_t)ch * 1024 * ksp) + 65536;
            if (need <= ws_size) { CH = ch; KSP = ksp; modeA = true; break; }
        }
    }
    if (!CH) {
        for (int ch = 65536; ch >= 128 && !CH; ch >>= 1) {
            for (int ksp = 2; ksp >= 1; --ksp) {
                size_t need = sortB + wB + xbB + al((size_t)ch * 4096) + al((size_t)ch * 1024 * ksp) + 65536;
                if (need <= ws_size) { CH = ch; KSP = ksp; modeA = false; break; }
            }
        }
    }
    if (!CH) { CH = 128; KSP = 1; modeA = false; }  // nothing fits; best effort

    char* ws = (char*)d_ws;
    size_t off = 0;
    auto alloc = [&](size_t bytes) -> void* {
        void* p = ws + off;
        off += al(bytes);
        return p;
    };
    u32* key0 = (u32*)alloc(NPTS * 4);
    u32* val0 = (u32*)alloc(NPTS * 4);
    u32* key1 = (u32*)alloc(NPTS * 4);
    u32* val1 = (u32*)alloc(NPTS * 4);
    u32* ghist = (u32*)alloc(256 * RG * 4);
    u32* aux = (u32*)alloc(64 * 4);
    u16* wqkv_b = (u16*)alloc((size_t)NLAYER * 3 * DMODEL * DMODEL * 2);
    u16* wo_b = (u16*)alloc((size_t)NLAYER * DMODEL * DMODEL * 2);
    u16* w1_b = (u16*)alloc((size_t)NLAYER * FFDIM * DMODEL * 2);
    u16* w2_b = (u16*)alloc((size_t)NLAYER * DMODEL * FFDIM * 2);
    u16* xb = (u16*)alloc((size_t)NPTS * DMODEL * 2);
    float* h = modeA ? (float*)alloc((size_t)NPTS * DMODEL * 4) : nullptr;
    u16* scratch1 = (u16*)alloc((size_t)CH * 4096);  // qkv (CH*768) + attout (CH*256) | ffn-mid (CH*2048)
    float* tmpc = (float*)alloc((size_t)CH * 1024 * KSP);  // KSP x (CH x 256) fp32 delta slices
    const size_t dstride = (size_t)CH * DMODEL;  // fp32 elems per slice

    // 1. morton keys
    morton_kernel<<<NPTS / 256, 256, 0, stream>>>(coords, key0, val0);

    // 2. stable radix sort, 3 x 8-bit passes (24-bit keys)
    u32 *ki = key0, *vi = val0, *ko = key1, *vo = val1;
    for (int p = 0; p < 3; ++p) {
        hist_kernel<<<RG, 256, 0, stream>>>(ki, ghist, p * 8);
        scan_up<<<64, 256, 0, stream>>>(ghist, aux);
        scatter_kernel<<<RG, 256, 0, stream>>>(ki, vi, ko, vo, ghist, aux, p * 8);
        u32* t;
        t = ki; ki = ko; ko = t;
        t = vi; vi = vo; vo = t;
    }
    const u32* idx = vi;  // sorted original indices

    // 3. weights -> bf16
    cvt_bf16_kernel<<<(NLAYER * 3 * DMODEL * DMODEL) / 256, 256, 0, stream>>>(Wqkv, wqkv_b, NLAYER * 3 * DMODEL * DMODEL);
    cvt_bf16_kernel<<<(NLAYER * DMODEL * DMODEL) / 256, 256, 0, stream>>>(Wo, wo_b, NLAYER * DMODEL * DMODEL);
    cvt_bf16_kernel<<<(NLAYER * FFDIM * DMODEL) / 256, 256, 0, stream>>>(W1, w1_b, NLAYER * FFDIM * DMODEL);
    cvt_bf16_kernel<<<(NLAYER * DMODEL * FFDIM) / 256, 256, 0, stream>>>(W2, w2_b, NLAYER * DMODEL * FFDIM);

    // 4. gather + PE
    if (modeA)
        gather_pe_kernel<true><<<NPTS / 4, 256, 0, stream>>>(idx, coords, feat, pex, pey, pez, pes, h, xb);
    else
        gather_pe_kernel<false><<<NPTS / 4, 256, 0, stream>>>(idx, coords, feat, pex, pey, pez, pes, nullptr, xb);

    // 5. encoder layers, chunked over rows (CH rows = CH/128 windows per chunk)
    const int nch = NPTS / CH;
    u16* qkvc = scratch1;                     // CH x 768 bf16
    u16* attoutc = scratch1 + (size_t)CH * 768;  // CH x 256 bf16
    u16* midc = scratch1;                     // CH x 2048 bf16 (reuses qkv region)
    for (int l = 0; l < NLAYER; ++l) {
        for (int c = 0; c < nch; ++c) {
            u16* xc = xb + (size_t)c * CH * DMODEL;
            float* hc = modeA ? h + (size_t)c * CH * DMODEL : nullptr;
            // qkv = x @ Wqkv^T + bqkv  -> bf16
            gemm_bt<false, true><<<dim3(CH / 128, (3 * DMODEL) / 128), 256, 0, stream>>>(
                xc, wqkv_b + (size_t)l * 3 * DMODEL * DMODEL, bqkv + (size_t)l * 3 * DMODEL, qkvc,
                CH, 3 * DMODEL, DMODEL);
            // window attention (MFMA) -> attout bf16
            attn_kernel<<<(CH / WSIZE) * NHEAD, 128, 0, stream>>>(qkvc, attoutc);
            // o = attout @ Wo^T + bo -> fp32
            gemm_bt<false, false><<<dim3(CH / 128, DMODEL / 128), 256, 0, stream>>>(
                attoutc, wo_b + (size_t)l * DMODEL * DMODEL, bo + (size_t)l * DMODEL, tmpc,
                CH, DMODEL, DMODEL);
            // h = LN(h + o)
            if (modeA)
                resid_ln_kernel<true, false, 1><<<CH / 4, 256, 0, stream>>>(hc, tmpc, g1 + (size_t)l * DMODEL,
                                                                            be1 + (size_t)l * DMODEL, hc, xc, dstride);
            else
                resid_ln_kernel<false, false, 1><<<CH / 4, 256, 0, stream>>>(xc, tmpc, g1 + (size_t)l * DMODEL,
                                                                             be1 + (size_t)l * DMODEL, nullptr, xc, dstride);
            // FFN
            gemm_bt<true, true><<<dim3(CH / 128, FFDIM / 128), 256, 0, stream>>>(
                xc, w1_b + (size_t)l * FFDIM * DMODEL, b1 + (size_t)l * FFDIM, midc,
                CH, FFDIM, DMODEL);
            gemm_bt<false, false><<<dim3(CH / 128, DMODEL / 128, KSP), 256, 0, stream>>>(
                midc, w2_b + (size_t)l * DMODEL * FFDIM, b2 + (size_t)l * DMODEL, tmpc,
                CH, DMODEL, FFDIM);
            // h = LN(h + ff)
            bool last = (l == NLAYER - 1);
            void* outc = last ? (void*)((float*)d_out + (size_t)c * CH * DMODEL) : (void*)xc;
            if (modeA) {
                if (last) {
                    if (KSP == 2)
                        resid_ln_kernel<true, true, 2><<<CH / 4, 256, 0, stream>>>(hc, tmpc, g2 + (size_t)l * DMODEL,
                                                                                   be2 + (size_t)l * DMODEL, hc, outc, dstride);
                    else
                        resid_ln_kernel<true, true, 1><<<CH / 4, 256, 0, stream>>>(hc, tmpc, g2 + (size_t)l * DMODEL,
                                                                                   be2 + (size_t)l * DMODEL, hc, outc, dstride);
                } else {
                    if (KSP == 2)
                        resid_ln_kernel<true, false, 2><<<CH / 4, 256, 0, stream>>>(hc, tmpc, g2 + (size_t)l * DMODEL,
                                                                                    be2 + (size_t)l * DMODEL, hc, outc, dstride);
                    else
                        resid_ln_kernel<true, false, 1><<<CH / 4, 256, 0, stream>>>(hc, tmpc, g2 + (size_t)l * DMODEL,
                                                                                    be2 + (size_t)l * DMODEL, hc, outc, dstride);
                }
            } else {
                if (last) {
                    if (KSP == 2)
                        resid_ln_kernel<false, true, 2><<<CH / 4, 256, 0, stream>>>(xc, tmpc, g2 + (size_t)l * DMODEL,
                                                                                    be2 + (size_t)l * DMODEL, nullptr, outc, dstride);
                    else
                        resid_ln_kernel<false, true, 1><<<CH / 4, 256, 0, stream>>>(xc, tmpc, g2 + (size_t)l * DMODEL,
                                                                                    be2 + (size_t)l * DMODEL, nullptr, outc, dstride);
                } else {
                    if (KSP == 2)
                        resid_ln_kernel<false, false, 2><<<CH / 4, 256, 0, stream>>>(xc, tmpc, g2 + (size_t)l * DMODEL,
                                                                                     be2 + (size_t)l * DMODEL, nullptr, outc, dstride);
                    else
                        resid_ln_kernel<false, false, 1><<<CH / 4, 256, 0, stream>>>(xc, tmpc, g2 + (size_t)l * DMODEL,
                                                                                     be2 + (size_t)l * DMODEL, nullptr, outc, dstride);
                }
            }
        }
    }
}

// Round 6
// 2213.818 us; speedup vs baseline: 1.2189x; 1.0786x over previous
//
#include <hip/hip_runtime.h>

typedef unsigned int u32;
typedef unsigned short u16;

#define NPTS 65536
#define DMODEL 256
#define NHEAD 8
#define DHEAD 32
#define NLAYER 4
#define FFDIM 2048
#define WSIZE 128
#define LNEPS 1e-5f
#define RG 256  // radix sort blocks (chunk = 256 elements each)

// LDS strides (bf16 elems) chosen to avoid systematic bank conflicts
#define KSTR 36
#define VSTR 132
#define PSTR 132

typedef __attribute__((ext_vector_type(8))) short short8;
typedef __attribute__((ext_vector_type(4))) float floatx4;

__device__ __forceinline__ float bf2f(u16 v) {
    u32 u = ((u32)v) << 16;
    float f;
    __builtin_memcpy(&f, &u, 4);
    return f;
}
__device__ __forceinline__ u16 f2bf(float f) {
    u32 u;
    __builtin_memcpy(&u, &f, 4);
    u32 r = (u + 0x7fffu + ((u >> 16) & 1u)) >> 16;
    return (u16)r;
}

__device__ __forceinline__ void gl_lds16(const void* g, void* l) {
    __builtin_amdgcn_global_load_lds((const __attribute__((address_space(1))) u32*)g,
                                     (__attribute__((address_space(3))) u32*)l, 16, 0, 0);
}

// ---------------- Morton keys + fused pass-0 histogram ----------------
__global__ __launch_bounds__(256) void morton_kernel(const int* __restrict__ coords,
                                                     u32* __restrict__ key, u32* __restrict__ val,
                                                     u32* __restrict__ ghist) {
    __shared__ u32 hh[256];
    int tid = threadIdx.x;
    hh[tid] = 0;
    int i = blockIdx.x * 256 + tid;
    int b = coords[4 * i + 0];
    int x = coords[4 * i + 1];
    int y = coords[4 * i + 2];
    int z = coords[4 * i + 3];
    u32 m = 0;
#pragma unroll
    for (int t = 0; t < 7; ++t) {
        m |= ((u32)((x >> t) & 1) << (3 * t + 2)) | ((u32)((y >> t) & 1) << (3 * t + 1)) |
             ((u32)((z >> t) & 1) << (3 * t));
    }
    u32 k = ((u32)b << 21) | m;
    key[i] = k;
    val[i] = (u32)i;
    __syncthreads();
    atomicAdd(&hh[k & 255u], 1u);
    __syncthreads();
    ghist[(size_t)tid * RG + blockIdx.x] = hh[tid];  // bucket-major, shift=0
}

// ---------------- radix sort (stable LSD, 3 x 8-bit) ----------------
__global__ __launch_bounds__(256) void hist_kernel(const u32* __restrict__ key, u32* __restrict__ ghist,
                                                   int shift) {
    __shared__ u32 h[256];
    int tid = threadIdx.x;
    h[tid] = 0;
    __syncthreads();
    u32 k = key[blockIdx.x * 256 + tid];
    atomicAdd(&h[(k >> shift) & 255u], 1u);
    __syncthreads();
    ghist[(size_t)tid * RG + blockIdx.x] = h[tid];  // bucket-major
}

// parallel exclusive scan over 256*RG = 65536 entries:
// scan_up: 64 blocks x 1024 entries -> in-place block-local exclusive scan + total to aux[64]
// (aux prefix is folded into scatter_kernel; no scan_down pass)
__global__ __launch_bounds__(256) void scan_up(u32* __restrict__ g, u32* __restrict__ aux) {
    __shared__ u32 wsum[4];
    int tid = threadIdx.x;
    int lane = tid & 63;
    int wave = tid >> 6;
    size_t base = (size_t)blockIdx.x * 1024 + (size_t)tid * 4;
    uint4 v = *(const uint4*)(g + base);
    u32 s = v.x + v.y + v.z + v.w;
    u32 inc = s;
#pragma unroll
    for (int off = 1; off < 64; off <<= 1) {
        u32 u = __shfl_up(inc, off, 64);
        if (lane >= off) inc += u;
    }
    if (lane == 63) wsum[wave] = inc;
    __syncthreads();
    u32 woff = 0;
    for (int w = 0; w < wave; ++w) woff += wsum[w];
    u32 excl = woff + inc - s;
    uint4 o;
    o.x = excl;
    o.y = excl + v.x;
    o.z = excl + v.x + v.y;
    o.w = excl + v.x + v.y + v.z;
    *(uint4*)(g + base) = o;
    if (tid == 255) aux[blockIdx.x] = woff + inc;  // block total
}

// scatter: stable rank via wave ballot multi-split + per-wave LDS histogram.
// Global bucket offset = block-local scanned ghist + wave-scanned aux prefix (fused scan_down).
__global__ __launch_bounds__(256) void scatter_kernel(const u32* __restrict__ keyin, const u32* __restrict__ valin,
                                                      u32* __restrict__ keyout, u32* __restrict__ valout,
                                                      const u32* __restrict__ ghist, const u32* __restrict__ aux,
                                                      int shift) {
    __shared__ u32 whist[4][256];
    __shared__ u32 apre[64];
    int tid = threadIdx.x;
    int lane = tid & 63;
    int wave = tid >> 6;
    uint4 z = {0u, 0u, 0u, 0u};
    ((uint4*)&whist[0][0])[tid] = z;
    if (tid < 64) {  // wave 0: exclusive scan of aux[64] into LDS
        u32 a = aux[tid];
        u32 inc = a;
#pragma unroll
        for (int off = 1; off < 64; off <<= 1) {
            u32 u = __shfl_up(inc, off, 64);
            if (lane >= off) inc += u;
        }
        apre[tid] = inc - a;
    }
    int gi = blockIdx.x * 256 + tid;
    u32 k = keyin[gi];
    u32 v = valin[gi];
    u32 b = (k >> shift) & 255u;
    __syncthreads();
    unsigned long long m = ~0ull;
#pragma unroll
    for (int bit = 0; bit < 8; ++bit) {
        unsigned long long bb = __ballot((int)((b >> bit) & 1u));
        m &= ((b >> bit) & 1u) ? bb : ~bb;
    }
    unsigned long long below = (lane == 0) ? 0ull : (m & ((1ull << lane) - 1ull));
    int rlane = __popcll(below);
    int cnt = __popcll(m);
    if (rlane == 0) whist[wave][b] = (u32)cnt;
    __syncthreads();
    u32 rank = (u32)rlane;
    for (int w = 0; w < wave; ++w) rank += whist[w][b];
    u32 e = b * (u32)RG + blockIdx.x;
    u32 dst = ghist[e] + apre[e >> 10] + rank;
    keyout[dst] = k;
    valout[dst] = v;
}

// ---------------- weights fp32 -> bf16, all 4 tensors in one dispatch ----------------
__global__ __launch_bounds__(256) void cvt_all_kernel(const float* __restrict__ s1, u16* __restrict__ d1, int n1,
                                                      const float* __restrict__ s2, u16* __restrict__ d2, int n2,
                                                      const float* __restrict__ s3, u16* __restrict__ d3, int n3,
                                                      const float* __restrict__ s4, u16* __restrict__ d4, int n4) {
    int i = blockIdx.x * 256 + threadIdx.x;
    if (i < n1) { d1[i] = f2bf(s1[i]); return; }
    i -= n1;
    if (i < n2) { d2[i] = f2bf(s2[i]); return; }
    i -= n2;
    if (i < n3) { d3[i] = f2bf(s3[i]); return; }
    i -= n3;
    if (i < n4) d4[i] = f2bf(s4[i]);
}

// ---------------- gather + positional encodings ----------------
template <bool HF32>
__global__ __launch_bounds__(256) void gather_pe_kernel(const u32* __restrict__ idx, const int* __restrict__ coords,
                                                        const float* __restrict__ feat,
                                                        const float* __restrict__ pex, const float* __restrict__ pey,
                                                        const float* __restrict__ pez, const float* __restrict__ pes,
                                                        float* __restrict__ h, u16* __restrict__ xb) {
    int row = blockIdx.x * 4 + (threadIdx.x >> 6);
    int lane = threadIdx.x & 63;
    int src = (int)idx[row];
    int cx = coords[4 * src + 1];
    int cy = coords[4 * src + 2];
    int cz = coords[4 * src + 3];
    int c = lane * 4;
    float4 f = *(const float4*)(feat + (size_t)src * DMODEL + c);
    float4 px = *(const float4*)(pex + (size_t)cx * DMODEL + c);
    float4 py = *(const float4*)(pey + (size_t)cy * DMODEL + c);
    float4 pz = *(const float4*)(pez + (size_t)cz * DMODEL + c);
    float4 ps = *(const float4*)(pes + (size_t)1 * DMODEL + c);  // pe_s[1]
    float4 r;
    r.x = f.x + px.x + py.x + pz.x + ps.x;
    r.y = f.y + px.y + py.y + pz.y + ps.y;
    r.z = f.z + px.z + py.z + pz.z + ps.z;
    r.w = f.w + px.w + py.w + pz.w + ps.w;
    if (HF32) *(float4*)(h + (size_t)row * DMODEL + c) = r;
    ushort4 o;
    o.x = f2bf(r.x);
    o.y = f2bf(r.y);
    o.z = f2bf(r.z);
    o.w = f2bf(r.w);
    *(ushort4*)(xb + (size_t)row * DMODEL + c) = o;
}

// ---------------- GEMM: C = A @ W^T + bias  (A: MxK bf16, W: OxK bf16) ----------------
// 128x128 tile, BK=32, 4 waves each 64x64 via 4x4 of 16x16x32 MFMA. 32 KB LDS dbuf ->
// 5 blocks/CU. Counted s_waitcnt vmcnt(4). Bank-conflict swizzle: source chunk
// s -> s ^ ((row>>1)&3) + same XOR on ds_read slot (2-way = free).
// Split-K via gridDim.z: slice kz -> Cout + kz*sz fp32; bias in slice 0 only.
template <bool RELU, bool BF16OUT>
__global__ __launch_bounds__(256, 5) void gemm_bt(const u16* __restrict__ A, const u16* __restrict__ W,
                                                  const float* __restrict__ bias, void* __restrict__ Cout,
                                                  int M, int O, int K, size_t sz) {
    __shared__ __align__(16) u16 lA[2 * 128 * 32];
    __shared__ __align__(16) u16 lB[2 * 128 * 32];
    const int tid = threadIdx.x;
    const int lane = tid & 63;
    const int wave = tid >> 6;
    const int wr = wave >> 1;
    const int wc = wave & 1;
    const int quad = lane >> 4;
    const int l16 = lane & 15;
    const int kz = blockIdx.z;
    const int Kpart = K / (int)gridDim.z;
    const size_t row0 = (size_t)blockIdx.x * 128;
    const size_t col0 = (size_t)blockIdx.y * 128;
    floatx4 acc[4][4] = {};

    const int r0 = tid >> 2;
    const int sg0 = (tid & 3) ^ ((r0 >> 1) & 3);  // inverse-swizzled source slot
    const u16* pA = A + (row0 + r0) * (size_t)K + (size_t)kz * Kpart + (sg0 << 3);
    const u16* pW = W + (col0 + r0) * (size_t)K + (size_t)kz * Kpart + (sg0 << 3);
    const size_t rstep = (size_t)64 * K;
    const int oA = tid * 8;

    const int nt = Kpart >> 5;
    gl_lds16(pA, lA + oA);
    gl_lds16(pA + rstep, lA + oA + 2048);
    gl_lds16(pW, lB + oA);
    gl_lds16(pW + rstep, lB + oA + 2048);
    pA += 32;
    pW += 32;

    const int sx = (quad ^ ((l16 >> 1) & 3)) << 3;  // read-side swizzled slot offset
    const int rdA = (wr * 64 + l16) * 32 + sx;
    const int rdB = (wc * 64 + l16) * 32 + sx;
    int buf = 0;
    for (int t = 0; t < nt; ++t) {
        if (t + 1 < nt) {
            const int nb = (buf ^ 1) * 4096;
            gl_lds16(pA, lA + nb + oA);
            gl_lds16(pA + rstep, lA + nb + oA + 2048);
            gl_lds16(pW, lB + nb + oA);
            gl_lds16(pW + rstep, lB + nb + oA + 2048);
            pA += 32;
            pW += 32;
            asm volatile("s_waitcnt vmcnt(4)" ::: "memory");
        } else {
            asm volatile("s_waitcnt vmcnt(0)" ::: "memory");
        }
        __builtin_amdgcn_s_barrier();
        const u16* la = lA + buf * 4096 + rdA;
        const u16* lb = lB + buf * 4096 + rdB;
        short8 af[4], bf[4];
#pragma unroll
        for (int r = 0; r < 4; ++r) af[r] = *(const short8*)(la + r * 512);
#pragma unroll
        for (int c = 0; c < 4; ++c) bf[c] = *(const short8*)(lb + c * 512);
#pragma unroll
        for (int r = 0; r < 4; ++r)
#pragma unroll
            for (int c = 0; c < 4; ++c)
                acc[r][c] = __builtin_amdgcn_mfma_f32_16x16x32_bf16(af[r], bf[c], acc[r][c], 0, 0, 0);
        if (t + 1 < nt) __builtin_amdgcn_s_barrier();
        buf ^= 1;
    }

    float* Cf = (float*)Cout + (size_t)kz * sz;
#pragma unroll
    for (int r = 0; r < 4; ++r) {
#pragma unroll
        for (int c = 0; c < 4; ++c) {
            size_t col = col0 + wc * 64 + c * 16 + l16;
            float bv = (kz == 0) ? bias[col] : 0.f;
#pragma unroll
            for (int reg = 0; reg < 4; ++reg) {
                size_t row = row0 + wr * 64 + r * 16 + quad * 4 + reg;
                float v = acc[r][c][reg] + bv;
                if (RELU) v = fmaxf(v, 0.f);
                if (BF16OUT)
                    ((u16*)Cout)[row * O + col] = f2bf(v);
                else
                    Cf[row * O + col] = v;
            }
        }
    }
}

// ---------------- wide GEMM for W1: 128x256 tile (relu, bf16 out) ----------------
// 4 waves each 64x128 -> 12 ds_read : 32 MFMA per K-tile (vs 8:16 at 128x128);
// barriers amortized over 2x FLOPs. 48 KB LDS, acc 4x8 -> ~200 VGPR, 2 blocks/CU.
__global__ __launch_bounds__(256, 2) void gemm_w1(const u16* __restrict__ A, const u16* __restrict__ W,
                                                  const float* __restrict__ bias, u16* __restrict__ Cout,
                                                  int O, int K) {
    __shared__ __align__(16) u16 lA[2 * 128 * 32];
    __shared__ __align__(16) u16 lB[2 * 256 * 32];
    const int tid = threadIdx.x;
    const int lane = tid & 63;
    const int wave = tid >> 6;
    const int wr = wave >> 1;
    const int wc = wave & 1;
    const int quad = lane >> 4;
    const int l16 = lane & 15;
    const size_t row0 = (size_t)blockIdx.x * 128;
    const size_t col0 = (size_t)blockIdx.y * 256;
    floatx4 acc[4][8] = {};

    const int r0 = tid >> 2;
    const int sg0 = (tid & 3) ^ ((r0 >> 1) & 3);
    const u16* pA = A + (row0 + r0) * (size_t)K + (sg0 << 3);
    const u16* pW = W + (col0 + r0) * (size_t)K + (sg0 << 3);
    const size_t rstep = (size_t)64 * K;
    const int oA = tid * 8;

    const int nt = K >> 5;
    // stage tile 0 -> buf 0: A rows r0,r0+64; B rows r0..r0+192
    gl_lds16(pA, lA + oA);
    gl_lds16(pA + rstep, lA + oA + 2048);
    gl_lds16(pW, lB + oA);
    gl_lds16(pW + rstep, lB + oA + 2048);
    gl_lds16(pW + 2 * rstep, lB + oA + 4096);
    gl_lds16(pW + 3 * rstep, lB + oA + 6144);
    pA += 32;
    pW += 32;

    const int sx = (quad ^ ((l16 >> 1) & 3)) << 3;
    const int rdA = (wr * 64 + l16) * 32 + sx;
    const int rdB = (wc * 128 + l16) * 32 + sx;
    int buf = 0;
    for (int t = 0; t < nt; ++t) {
        if (t + 1 < nt) {
            const int na = (buf ^ 1) * 4096;
            const int nb = (buf ^ 1) * 8192;
            gl_lds16(pA, lA + na + oA);
            gl_lds16(pA + rstep, lA + na + oA + 2048);
            gl_lds16(pW, lB + nb + oA);
            gl_lds16(pW + rstep, lB + nb + oA + 2048);
            gl_lds16(pW + 2 * rstep, lB + nb + oA + 4096);
            gl_lds16(pW + 3 * rstep, lB + nb + oA + 6144);
            pA += 32;
            pW += 32;
            asm volatile("s_waitcnt vmcnt(6)" ::: "memory");
        } else {
            asm volatile("s_waitcnt vmcnt(0)" ::: "memory");
        }
        __builtin_amdgcn_s_barrier();
        const u16* la = lA + buf * 4096 + rdA;
        const u16* lb = lB + buf * 8192 + rdB;
        short8 af[4], bf[8];
#pragma unroll
        for (int r = 0; r < 4; ++r) af[r] = *(const short8*)(la + r * 512);
#pragma unroll
        for (int c = 0; c < 8; ++c) bf[c] = *(const short8*)(lb + c * 512);
#pragma unroll
        for (int r = 0; r < 4; ++r)
#pragma unroll
            for (int c = 0; c < 8; ++c)
                acc[r][c] = __builtin_amdgcn_mfma_f32_16x16x32_bf16(af[r], bf[c], acc[r][c], 0, 0, 0);
        if (t + 1 < nt) __builtin_amdgcn_s_barrier();
        buf ^= 1;
    }

#pragma unroll
    for (int r = 0; r < 4; ++r) {
#pragma unroll
        for (int c = 0; c < 8; ++c) {
            size_t col = col0 + wc * 128 + c * 16 + l16;
            float bv = bias[col];
#pragma unroll
            for (int reg = 0; reg < 4; ++reg) {
                size_t row = row0 + wr * 64 + r * 16 + quad * 4 + reg;
                float v = fmaxf(acc[r][c][reg] + bv, 0.f);
                Cout[row * O + col] = f2bf(v);
            }
        }
    }
}

// ---------------- window attention, MFMA (one block = one (window, head)) ----------------
__global__ __launch_bounds__(128) void attn_kernel(const u16* __restrict__ qkv, u16* __restrict__ outb) {
    const int wh = blockIdx.x;
    const int w = wh >> 3;
    const int h = wh & 7;
    const int tid = threadIdx.x;
    const int wave = tid >> 6;
    const int lane = tid & 63;
    const int quad = lane >> 4;
    const int l16 = lane & 15;
    __shared__ __align__(16) u16 lK[128 * KSTR];
    __shared__ __align__(16) u16 lVt[32 * VSTR];
    __shared__ __align__(16) u16 lP[128 * PSTR];
    const u16* base = qkv + (size_t)w * WSIZE * (3 * DMODEL);

    {
        const u16* krow = base + (size_t)tid * (3 * DMODEL) + DMODEL + h * DHEAD;
        const u16* vrow = base + (size_t)tid * (3 * DMODEL) + 2 * DMODEL + h * DHEAD;
#pragma unroll
        for (int p = 0; p < 4; ++p)
            *(short8*)&lK[tid * KSTR + p * 8] = *(const short8*)(krow + p * 8);
        u16 varr[32];
#pragma unroll
        for (int p = 0; p < 4; ++p)
            *(short8*)&varr[p * 8] = *(const short8*)(vrow + p * 8);
#pragma unroll
        for (int d = 0; d < DHEAD; ++d) lVt[d * VSTR + tid] = varr[d];
    }
    short8 af[4];
#pragma unroll
    for (int mi = 0; mi < 4; ++mi)
        af[mi] = *(const short8*)(base + (size_t)(wave * 64 + mi * 16 + l16) * (3 * DMODEL) + h * DHEAD + quad * 8);
    __syncthreads();

    floatx4 acc[4][8] = {};
#pragma unroll
    for (int ni = 0; ni < 8; ++ni) {
        short8 bk = *(const short8*)&lK[(ni * 16 + l16) * KSTR + quad * 8];
#pragma unroll
        for (int mi = 0; mi < 4; ++mi)
            acc[mi][ni] = __builtin_amdgcn_mfma_f32_16x16x32_bf16(af[mi], bk, acc[mi][ni], 0, 0, 0);
    }

    const float scale = 0.17677669529663687f;  // 1/sqrt(32)
    float inv[4][4];
#pragma unroll
    for (int mi = 0; mi < 4; ++mi) {
#pragma unroll
        for (int reg = 0; reg < 4; ++reg) {
            float m = acc[mi][0][reg];
#pragma unroll
            for (int ni = 1; ni < 8; ++ni) m = fmaxf(m, acc[mi][ni][reg]);
            m = fmaxf(m, __shfl_xor(m, 1, 64));
            m = fmaxf(m, __shfl_xor(m, 2, 64));
            m = fmaxf(m, __shfl_xor(m, 4, 64));
            m = fmaxf(m, __shfl_xor(m, 8, 64));
            float e[8];
            float sum = 0.f;
#pragma unroll
            for (int ni = 0; ni < 8; ++ni) {
                e[ni] = __expf((acc[mi][ni][reg] - m) * scale);
                sum += e[ni];
            }
            sum += __shfl_xor(sum, 1, 64);
            sum += __shfl_xor(sum, 2, 64);
            sum += __shfl_xor(sum, 4, 64);
            sum += __shfl_xor(sum, 8, 64);
            inv[mi][reg] = 1.f / sum;
            int row = wave * 64 + mi * 16 + quad * 4 + reg;
#pragma unroll
            for (int ni = 0; ni < 8; ++ni) lP[row * PSTR + ni * 16 + l16] = f2bf(e[ni]);
        }
    }

    floatx4 acc2[4][2] = {};
#pragma unroll
    for (int kt = 0; kt < 4; ++kt) {
        short8 pa[4];
#pragma unroll
        for (int mi = 0; mi < 4; ++mi)
            pa[mi] = *(const short8*)&lP[(wave * 64 + mi * 16 + l16) * PSTR + kt * 32 + quad * 8];
#pragma unroll
        for (int c = 0; c < 2; ++c) {
            short8 bv = *(const short8*)&lVt[(c * 16 + l16) * VSTR + kt * 32 + quad * 8];
#pragma unroll
            for (int mi = 0; mi < 4; ++mi)
                acc2[mi][c] = __builtin_amdgcn_mfma_f32_16x16x32_bf16(pa[mi], bv, acc2[mi][c], 0, 0, 0);
        }
    }

#pragma unroll
    for (int mi = 0; mi < 4; ++mi) {
#pragma unroll
        for (int c = 0; c < 2; ++c) {
#pragma unroll
            for (int reg = 0; reg < 4; ++reg) {
                int row = wave * 64 + mi * 16 + quad * 4 + reg;
                outb[(size_t)(w * WSIZE + row) * DMODEL + h * DHEAD + c * 16 + l16] =
                    f2bf(acc2[mi][c][reg] * inv[mi][reg]);
            }
        }
    }
}

// ---------------- residual add + LayerNorm ----------------
template <bool HF32, bool OUTF32, int NS>
__global__ __launch_bounds__(256) void resid_ln_kernel(const void* __restrict__ hin, const float* __restrict__ delta,
                                                       const float* __restrict__ g, const float* __restrict__ b,
                                                       float* __restrict__ hout, void* __restrict__ nout,
                                                       size_t dstride) {
    int row = blockIdx.x * 4 + (threadIdx.x >> 6);
    int lane = threadIdx.x & 63;
    int c = lane * 4;
    float4 x;
    if (HF32) {
        x = *(const float4*)((const float*)hin + (size_t)row * DMODEL + c);
    } else {
        ushort4 hv = *(const ushort4*)((const u16*)hin + (size_t)row * DMODEL + c);
        x.x = bf2f(hv.x);
        x.y = bf2f(hv.y);
        x.z = bf2f(hv.z);
        x.w = bf2f(hv.w);
    }
    float4 d = *(const float4*)(delta + (size_t)row * DMODEL + c);
    if (NS == 2) {
        float4 d2 = *(const float4*)(delta + dstride + (size_t)row * DMODEL + c);
        d.x += d2.x;
        d.y += d2.y;
        d.z += d2.z;
        d.w += d2.w;
    }
    x.x += d.x;
    x.y += d.y;
    x.z += d.z;
    x.w += d.w;
    float s = x.x + x.y + x.z + x.w;
#pragma unroll
    for (int off = 32; off > 0; off >>= 1) s += __shfl_xor(s, off, 64);
    float mu = s * (1.f / 256.f);
    float d0 = x.x - mu, d1 = x.y - mu, d2 = x.z - mu, d3 = x.w - mu;
    float vs = d0 * d0 + d1 * d1 + d2 * d2 + d3 * d3;
#pragma unroll
    for (int off = 32; off > 0; off >>= 1) vs += __shfl_xor(vs, off, 64);
    float rs = rsqrtf(vs * (1.f / 256.f) + LNEPS);
    float4 gg = *(const float4*)(g + c);
    float4 bb = *(const float4*)(b + c);
    float4 y;
    y.x = d0 * rs * gg.x + bb.x;
    y.y = d1 * rs * gg.y + bb.y;
    y.z = d2 * rs * gg.z + bb.z;
    y.w = d3 * rs * gg.w + bb.w;
    if (HF32) *(float4*)(hout + (size_t)row * DMODEL + c) = y;
    if (OUTF32) {
        *(float4*)((float*)nout + (size_t)row * DMODEL + c) = y;
    } else {
        ushort4 o;
        o.x = f2bf(y.x);
        o.y = f2bf(y.y);
        o.z = f2bf(y.z);
        o.w = f2bf(y.w);
        *(ushort4*)((u16*)nout + (size_t)row * DMODEL + c) = o;
    }
}

// ---------------- launch ----------------
extern "C" void kernel_launch(void* const* d_in, const int* in_sizes, int n_in,
                              void* d_out, int out_size, void* d_ws, size_t ws_size,
                              hipStream_t stream) {
    (void)in_sizes;
    (void)n_in;
    (void)out_size;
    const int* coords = (const int*)d_in[0];
    const float* feat = (const float*)d_in[1];
    const float* pex = (const float*)d_in[2];
    const float* pey = (const float*)d_in[3];
    const float* pez = (const float*)d_in[4];
    const float* pes = (const float*)d_in[5];
    const float* Wqkv = (const float*)d_in[6];
    const float* bqkv = (const float*)d_in[7];
    const float* Wo = (const float*)d_in[8];
    const float* bo = (const float*)d_in[9];
    const float* W1 = (const float*)d_in[10];
    const float* b1 = (const float*)d_in[11];
    const float* W2 = (const float*)d_in[12];
    const float* b2 = (const float*)d_in[13];
    const float* g1 = (const float*)d_in[14];
    const float* be1 = (const float*)d_in[15];
    const float* g2 = (const float*)d_in[16];
    const float* be2 = (const float*)d_in[17];

    auto al = [](size_t x) { return (x + 255) & ~(size_t)255; };
    const size_t sortB = 4 * al((size_t)NPTS * 4) + al((size_t)256 * RG * 4) + 256;
    const size_t wqkvB = al((size_t)NLAYER * 3 * DMODEL * DMODEL * 2);
    const size_t woB = al((size_t)NLAYER * DMODEL * DMODEL * 2);
    const size_t w1B = al((size_t)NLAYER * FFDIM * DMODEL * 2);
    const size_t w2B = al((size_t)NLAYER * DMODEL * FFDIM * 2);
    const size_t wB = wqkvB + woB + w1B + w2B;
    const size_t xbB = al((size_t)NPTS * DMODEL * 2);
    const size_t hB = al((size_t)NPTS * DMODEL * 4);

    // choose mode + chunk size + split-K to fit ws_size.
    // scratch1 = CH*2048 B (qkv CH*1536 + attout CH*512; FFN runs in 2 M-halves so mid
    // (CH/2 * 4096 B) reuses the same region). Priority: larger CH > split-K=2 for W2.
    int CH = 0, KSP = 1;
    bool modeA = true;
    for (int ch = 65536; ch >= 256 && !CH; ch >>= 1) {
        for (int ksp = 2; ksp >= 1; --ksp) {
            size_t need = sortB + wB + xbB + hB + al((size_t)ch * 2048) + al((size_t)ch * 1024 * ksp) + 65536;
            if (need <= ws_size) { CH = ch; KSP = ksp; modeA = true; break; }
        }
    }
    if (!CH) {
        for (int ch = 65536; ch >= 256 && !CH; ch >>= 1) {
            for (int ksp = 2; ksp >= 1; --ksp) {
                size_t need = sortB + wB + xbB + al((size_t)ch * 2048) + al((size_t)ch * 1024 * ksp) + 65536;
                if (need <= ws_size) { CH = ch; KSP = ksp; modeA = false; break; }
            }
        }
    }
    if (!CH) { CH = 256; KSP = 1; modeA = false; }  // nothing fits; best effort

    char* ws = (char*)d_ws;
    size_t off = 0;
    auto alloc = [&](size_t bytes) -> void* {
        void* p = ws + off;
        off += al(bytes);
        return p;
    };
    u32* key0 = (u32*)alloc(NPTS * 4);
    u32* val0 = (u32*)alloc(NPTS * 4);
    u32* key1 = (u32*)alloc(NPTS * 4);
    u32* val1 = (u32*)alloc(NPTS * 4);
    u32* ghist = (u32*)alloc(256 * RG * 4);
    u32* aux = (u32*)alloc(64 * 4);
    u16* wqkv_b = (u16*)alloc((size_t)NLAYER * 3 * DMODEL * DMODEL * 2);
    u16* wo_b = (u16*)alloc((size_t)NLAYER * DMODEL * DMODEL * 2);
    u16* w1_b = (u16*)alloc((size_t)NLAYER * FFDIM * DMODEL * 2);
    u16* w2_b = (u16*)alloc((size_t)NLAYER * DMODEL * FFDIM * 2);
    u16* xb = (u16*)alloc((size_t)NPTS * DMODEL * 2);
    float* h = modeA ? (float*)alloc((size_t)NPTS * DMODEL * 4) : nullptr;
    u16* scratch1 = (u16*)alloc((size_t)CH * 2048);       // qkv + attout | ffn-mid half-chunk
    float* tmpc = (float*)alloc((size_t)CH * 1024 * KSP); // KSP x (CH x 256) fp32 delta slices
    const size_t dstride = (size_t)CH * DMODEL;           // fp32 elems per slice

    // 1. morton keys + pass-0 histogram (fused)
    morton_kernel<<<NPTS / 256, 256, 0, stream>>>(coords, key0, val0, ghist);

    // 2. stable radix sort, 3 x 8-bit passes
    u32 *ki = key0, *vi = val0, *ko = key1, *vo = val1;
    for (int p = 0; p < 3; ++p) {
        if (p > 0) hist_kernel<<<RG, 256, 0, stream>>>(ki, ghist, p * 8);
        scan_up<<<64, 256, 0, stream>>>(ghist, aux);
        scatter_kernel<<<RG, 256, 0, stream>>>(ki, vi, ko, vo, ghist, aux, p * 8);
        u32* t;
        t = ki; ki = ko; ko = t;
        t = vi; vi = vo; vo = t;
    }
    const u32* idx = vi;  // sorted original indices

    // 3. weights -> bf16 (one dispatch)
    {
        const int n1 = NLAYER * 3 * DMODEL * DMODEL;
        const int n2 = NLAYER * DMODEL * DMODEL;
        const int n3 = NLAYER * FFDIM * DMODEL;
        const int n4 = NLAYER * DMODEL * FFDIM;
        cvt_all_kernel<<<(n1 + n2 + n3 + n4) / 256, 256, 0, stream>>>(Wqkv, wqkv_b, n1, Wo, wo_b, n2,
                                                                      W1, w1_b, n3, W2, w2_b, n4);
    }

    // 4. gather + PE
    if (modeA)
        gather_pe_kernel<true><<<NPTS / 4, 256, 0, stream>>>(idx, coords, feat, pex, pey, pez, pes, h, xb);
    else
        gather_pe_kernel<false><<<NPTS / 4, 256, 0, stream>>>(idx, coords, feat, pex, pey, pez, pes, nullptr, xb);

    // 5. encoder layers, chunked over rows
    const int nch = NPTS / CH;
    u16* qkvc = scratch1;                        // CH x 768 bf16
    u16* attoutc = scratch1 + (size_t)CH * 768;  // CH x 256 bf16
    u16* midc = scratch1;                        // CH/2 x 2048 bf16 (reuses qkv region)
    for (int l = 0; l < NLAYER; ++l) {
        for (int c = 0; c < nch; ++c) {
            u16* xc = xb + (size_t)c * CH * DMODEL;
            float* hc = modeA ? h + (size_t)c * CH * DMODEL : nullptr;
            // qkv = x @ Wqkv^T + bqkv -> bf16
            gemm_bt<false, true><<<dim3(CH / 128, (3 * DMODEL) / 128), 256, 0, stream>>>(
                xc, wqkv_b + (size_t)l * 3 * DMODEL * DMODEL, bqkv + (size_t)l * 3 * DMODEL, qkvc,
                CH, 3 * DMODEL, DMODEL, 0);
            // window attention -> attout bf16
            attn_kernel<<<(CH / WSIZE) * NHEAD, 128, 0, stream>>>(qkvc, attoutc);
            // o = attout @ Wo^T + bo -> fp32
            gemm_bt<false, false><<<dim3(CH / 128, DMODEL / 128), 256, 0, stream>>>(
                attoutc, wo_b + (size_t)l * DMODEL * DMODEL, bo + (size_t)l * DMODEL, tmpc,
                CH, DMODEL, DMODEL, 0);
            // h = LN(h + o)
            if (modeA)
                resid_ln_kernel<true, false, 1><<<CH / 4, 256, 0, stream>>>(hc, tmpc, g1 + (size_t)l * DMODEL,
                                                                            be1 + (size_t)l * DMODEL, hc, xc, dstride);
            else
                resid_ln_kernel<false, false, 1><<<CH / 4, 256, 0, stream>>>(xc, tmpc, g1 + (size_t)l * DMODEL,
                                                                             be1 + (size_t)l * DMODEL, nullptr, xc, dstride);
            // FFN in two M-halves (mid buffer = half chunk)
            const int MH = CH / 2;
            for (int hf = 0; hf < 2; ++hf) {
                const u16* xh = xc + (size_t)hf * MH * DMODEL;
                gemm_w1<<<dim3(MH / 128, FFDIM / 256), 256, 0, stream>>>(
                    xh, w1_b + (size_t)l * FFDIM * DMODEL, b1 + (size_t)l * FFDIM, midc, FFDIM, DMODEL);
                gemm_bt<false, false><<<dim3(MH / 128, DMODEL / 128, KSP), 256, 0, stream>>>(
                    midc, w2_b + (size_t)l * DMODEL * FFDIM, b2 + (size_t)l * DMODEL,
                    tmpc + (size_t)hf * MH * DMODEL, MH, DMODEL, FFDIM, dstride);
            }
            // h = LN(h + ff)
            bool last = (l == NLAYER - 1);
            void* outc = last ? (void*)((float*)d_out + (size_t)c * CH * DMODEL) : (void*)xc;
            if (modeA) {
                if (last) {
                    if (KSP == 2)
                        resid_ln_kernel<true, true, 2><<<CH / 4, 256, 0, stream>>>(hc, tmpc, g2 + (size_t)l * DMODEL,
                                                                                   be2 + (size_t)l * DMODEL, hc, outc, dstride);
                    else
                        resid_ln_kernel<true, true, 1><<<CH / 4, 256, 0, stream>>>(hc, tmpc, g2 + (size_t)l * DMODEL,
                                                                                   be2 + (size_t)l * DMODEL, hc, outc, dstride);
                } else {
                    if (KSP == 2)
                        resid_ln_kernel<true, false, 2><<<CH / 4, 256, 0, stream>>>(hc, tmpc, g2 + (size_t)l * DMODEL,
                                                                                    be2 + (size_t)l * DMODEL, hc, outc, dstride);
                    else
                        resid_ln_kernel<true, false, 1><<<CH / 4, 256, 0, stream>>>(hc, tmpc, g2 + (size_t)l * DMODEL,
                                                                                    be2 + (size_t)l * DMODEL, hc, outc, dstride);
                }
            } else {
                if (last) {
                    if (KSP == 2)
                        resid_ln_kernel<false, true, 2><<<CH / 4, 256, 0, stream>>>(xc, tmpc, g2 + (size_t)l * DMODEL,
                                                                                    be2 + (size_t)l * DMODEL, nullptr, outc, dstride);
                    else
                        resid_ln_kernel<false, true, 1><<<CH / 4, 256, 0, stream>>>(xc, tmpc, g2 + (size_t)l * DMODEL,
                                                                                    be2 + (size_t)l * DMODEL, nullptr, outc, dstride);
                } else {
                    if (KSP == 2)
                        resid_ln_kernel<false, false, 2><<<CH / 4, 256, 0, stream>>>(xc, tmpc, g2 + (size_t)l * DMODEL,
                                                                                     be2 + (size_t)l * DMODEL, nullptr, outc, dstride);
                    else
                        resid_ln_kernel<false, false, 1><<<CH / 4, 256, 0, stream>>>(xc, tmpc, g2 + (size_t)l * DMODEL,
                                                                                     be2 + (size_t)l * DMODEL, nullptr, outc, dstride);
                }
            }
        }
    }
}